// Round 1
// baseline (1093.743 us; speedup 1.0000x reference)
//
#include <hip/hip_runtime.h>
#include <cmath>

// Problem constants
constexpr int BB = 4, LL = 8, NPTS = 4096, MQ = 1024, KNNK = 16;
constexpr int C1 = 64, C2 = 128;
constexpr int NSLICE = BB * LL;                       // 32
constexpr long long SAMP = (long long)NSLICE * MQ * KNNK;  // 524288 samples
constexpr int NBLK_ZZ = 512;
constexpr int ZZW = C1 * C1 + C1;                     // 4160 (full 64x64 + sum_z)

// Workspace layout (bytes)
constexpr size_t OFF_G    = 0;                                   // float4[SAMP] = 8 MB
constexpr size_t OFF_GMOM = (size_t)8 * 1024 * 1024;             // float[256*9]
constexpr size_t OFF_S1   = OFF_GMOM + 16384;                    // float[128]: scale1,shift1
constexpr size_t OFF_ZZP  = OFF_S1 + 1024;                       // float[NBLK_ZZ*ZZW]
constexpr size_t OFF_ZZS  = OFF_ZZP + (size_t)NBLK_ZZ * ZZW * 4; // double[ZZW]
constexpr size_t OFF_S2   = OFF_ZZS + (size_t)ZZW * 8;           // float[256]: scale2,shift2
// total ~16.95 MB

// ---------------------------------------------------------------------------
// K1: per-slice KNN + gather + per-block coord moments.
// 256 blocks (32 slices x 8 query-tiles), 256 threads. 2 lanes per query.
// d2 arithmetic replicates the reference: p2/q2 plain (no fma), pq fma-chain,
// final combine (q2+p2) - 2*pq (fma(-2,pq,t) is bit-identical since 2*pq exact).
// ---------------------------------------------------------------------------
__global__ __launch_bounds__(256) void knn_kernel(const float* __restrict__ pts,
                                                  const float* __restrict__ qrs,
                                                  float4* __restrict__ G,
                                                  float* __restrict__ gmom)
{
#pragma clang fp contract(off)
  __shared__ float4 sp[NPTS];   // (x,y,z,p2)  = 64 KB
  const int tid = threadIdx.x;
  const int bl = blockIdx.x >> 3;   // slice
  const int qt = blockIdx.x & 7;    // query tile (128 queries)

  const float* pb = pts + (size_t)bl * NPTS * 3;
  for (int p = tid; p < NPTS; p += 256) {
    float x = pb[p * 3 + 0], y = pb[p * 3 + 1], z = pb[p * 3 + 2];
    float pp = (x * x + y * y) + z * z;       // plain rounding
    sp[p] = make_float4(x, y, z, pp);
  }
  __syncthreads();

  const int pair = tid >> 1;
  const int half = tid & 1;
  const int q = qt * 128 + pair;
  const float* qp = qrs + ((size_t)bl * MQ + q) * 3;
  const float qx = qp[0], qy = qp[1], qz = qp[2];
  const float q2 = (qx * qx + qy * qy) + qz * qz;   // plain rounding

  float kd[16]; int ki[16];
#pragma unroll
  for (int j = 0; j < 16; ++j) { kd[j] = 3.402823466e38f; ki[j] = 0; }

  const int n0 = half * 2048;
#pragma unroll 4
  for (int n = 0; n < 2048; ++n) {
    float4 P = sp[n0 + n];
    float pq = fmaf(P.z, qz, fmaf(P.y, qy, P.x * qx));  // gemm-style fma chain
    float t = q2 + P.w;
    float d = fmaf(-2.0f, pq, t);                       // == t - 2*pq exactly
    if (d < kd[15]) {                                   // strict: keeps lower idx on tie
      kd[15] = d; ki[15] = n0 + n;
#pragma unroll
      for (int j = 15; j > 0; --j) {
        float da = kd[j - 1], db = kd[j];
        int   ia = ki[j - 1], ib = ki[j];
        bool sw = db < da;                              // strict: stable
        kd[j - 1] = sw ? db : da; kd[j] = sw ? da : db;
        ki[j - 1] = sw ? ib : ia; ki[j] = sw ? ia : ib;
      }
    }
  }

  // exchange lists with partner lane, lexicographic bitonic merge (exact ties by index)
  float od[16]; int oi[16];
#pragma unroll
  for (int j = 0; j < 16; ++j) {
    od[j] = __shfl_xor(kd[j], 1, 64);
    oi[j] = __shfl_xor(ki[j], 1, 64);
  }
  float md[16]; int mi[16];
#pragma unroll
  for (int j = 0; j < 16; ++j) {
    float ad = half ? od[j] : kd[j];        int ai = half ? oi[j] : ki[j];
    float bd = half ? kd[15 - j] : od[15 - j]; int bi = half ? ki[15 - j] : oi[15 - j];
    bool bless = (bd < ad) || (bd == ad && bi < ai);
    md[j] = bless ? bd : ad; mi[j] = bless ? bi : ai;
  }
#pragma unroll
  for (int k = 8; k >= 1; k >>= 1) {
#pragma unroll
    for (int j = 0; j < 16; ++j) {
      if ((j & k) == 0) {
        int a = j, b = j | k;
        float da = md[a], db = md[b];
        int   ia = mi[a], ib = mi[b];
        bool sw = (db < da) || (db == da && ib < ia);
        md[a] = sw ? db : da; md[b] = sw ? da : db;
        mi[a] = sw ? ib : ia; mi[b] = sw ? ia : ib;
      }
    }
  }

  // gather write + per-query coord moments (even lane only)
  float s0 = 0, s1 = 0, s2 = 0, s3 = 0, s4 = 0, s5 = 0, s6 = 0, s7 = 0, s8 = 0;
  if (!half) {
    size_t base = ((size_t)bl * MQ + q) * KNNK;
#pragma unroll
    for (int j = 0; j < 16; ++j) {
      float4 P = sp[mi[j]];
      G[base + j] = make_float4(P.x, P.y, P.z, 0.0f);
      s0 += P.x; s1 += P.y; s2 += P.z;
      s3 = fmaf(P.x, P.x, s3); s4 = fmaf(P.y, P.y, s4); s5 = fmaf(P.z, P.z, s5);
      s6 = fmaf(P.x, P.y, s6); s7 = fmaf(P.x, P.z, s7); s8 = fmaf(P.y, P.z, s8);
    }
  }
  __syncthreads();               // done with sp as points: reuse for reduction
  float* sr = (float*)sp;
  if (!half) {
    sr[pair * 9 + 0] = s0; sr[pair * 9 + 1] = s1; sr[pair * 9 + 2] = s2;
    sr[pair * 9 + 3] = s3; sr[pair * 9 + 4] = s4; sr[pair * 9 + 5] = s5;
    sr[pair * 9 + 6] = s6; sr[pair * 9 + 7] = s7; sr[pair * 9 + 8] = s8;
  }
  __syncthreads();
  if (tid < 9) {
    float acc = 0;
    for (int r = 0; r < 128; ++r) acc += sr[r * 9 + tid];
    gmom[blockIdx.x * 9 + tid] = acc;
  }
}

// ---------------------------------------------------------------------------
// K2: stats1 — analytic BN1 stats from coord moments (1 block, 64 threads)
// ---------------------------------------------------------------------------
__global__ void stats1_kernel(const float* __restrict__ gmom,
                              const float* __restrict__ W1, const float* __restrict__ b1,
                              const float* __restrict__ g1, const float* __restrict__ be1,
                              float* __restrict__ s1out)
{
  __shared__ double m[9];
  if (threadIdx.x < 9) {
    double s = 0;
    for (int r = 0; r < 256; ++r) s += (double)gmom[r * 9 + threadIdx.x];
    m[threadIdx.x] = s / (double)SAMP;
  }
  __syncthreads();
  int c = threadIdx.x;  // 0..63
  double Ex = m[0], Ey = m[1], Ez = m[2];
  double Exx = m[3], Eyy = m[4], Ezz = m[5], Exy = m[6], Exz = m[7], Eyz = m[8];
  double wx = W1[c * 3 + 0], wy = W1[c * 3 + 1], wz = W1[c * 3 + 2], b = b1[c];
  double dot = wx * Ex + wy * Ey + wz * Ez;
  double mean = dot + b;
  double Ey2 = wx * wx * Exx + wy * wy * Eyy + wz * wz * Ezz
             + 2.0 * (wx * wy * Exy + wx * wz * Exz + wy * wz * Eyz)
             + 2.0 * b * dot + b * b;
  double var = Ey2 - mean * mean;
  double sc = (double)g1[c] / sqrt(var + 1e-5);
  s1out[c] = (float)sc;
  s1out[64 + c] = (float)((double)be1[c] - mean * sc);
}

// ---------------------------------------------------------------------------
// K3: z moments — recompute z1 from G, accumulate sum_z (64) and sum z z^T (64x64)
// 512 blocks x 256 threads, each block owns 1024 samples (8 tiles of 128).
// ---------------------------------------------------------------------------
__global__ __launch_bounds__(256) void zmom_kernel(const float4* __restrict__ G,
                                                   const float* __restrict__ W1,
                                                   const float* __restrict__ b1,
                                                   const float* __restrict__ s1,
                                                   float* __restrict__ zzp)
{
  __shared__ float zt[128][68];     // 34816 B, rows 16B-aligned (68*4=272=17*16)
  __shared__ float szred[4][64];

  const int tid = threadIdx.x;
  const int c = tid & 63;           // z channel this thread computes
  const int srow = tid >> 6;        // 0..3
  const float w1x = W1[c * 3 + 0], w1y = W1[c * 3 + 1], w1z = W1[c * 3 + 2];
  const float bb = b1[c], sc = s1[c], sh = s1[64 + c];

  const int R = tid >> 4;           // 0..15 (rows of 4)
  const int C = tid & 15;           // 0..15 (cols of 4)
  float acc[4][4];
#pragma unroll
  for (int i = 0; i < 4; ++i)
#pragma unroll
    for (int j = 0; j < 4; ++j) acc[i][j] = 0.0f;
  float szpart = 0.0f;

  const size_t sbase = (size_t)blockIdx.x * 1024;
  for (int t = 0; t < 8; ++t) {
    size_t s0 = sbase + (size_t)t * 128;
    // phase 1: stage 128 z rows
#pragma unroll 4
    for (int k = 0; k < 32; ++k) {
      int sl = srow + k * 4;
      float4 g = G[s0 + sl];
      float y = fmaf(w1z, g.z, fmaf(w1y, g.y, fmaf(w1x, g.x, bb)));
      float z = fmaxf(fmaf(sc, y, sh), 0.0f);
      zt[sl][c] = z;
      szpart += z;
    }
    __syncthreads();
    // phase 2: outer-product accumulate
#pragma unroll 4
    for (int s = 0; s < 128; ++s) {
      float4 va = *(const float4*)&zt[s][R * 4];
      float4 vb = *(const float4*)&zt[s][C * 4];
      acc[0][0] = fmaf(va.x, vb.x, acc[0][0]); acc[0][1] = fmaf(va.x, vb.y, acc[0][1]);
      acc[0][2] = fmaf(va.x, vb.z, acc[0][2]); acc[0][3] = fmaf(va.x, vb.w, acc[0][3]);
      acc[1][0] = fmaf(va.y, vb.x, acc[1][0]); acc[1][1] = fmaf(va.y, vb.y, acc[1][1]);
      acc[1][2] = fmaf(va.y, vb.z, acc[1][2]); acc[1][3] = fmaf(va.y, vb.w, acc[1][3]);
      acc[2][0] = fmaf(va.z, vb.x, acc[2][0]); acc[2][1] = fmaf(va.z, vb.y, acc[2][1]);
      acc[2][2] = fmaf(va.z, vb.z, acc[2][2]); acc[2][3] = fmaf(va.z, vb.w, acc[2][3]);
      acc[3][0] = fmaf(va.w, vb.x, acc[3][0]); acc[3][1] = fmaf(va.w, vb.y, acc[3][1]);
      acc[3][2] = fmaf(va.w, vb.z, acc[3][2]); acc[3][3] = fmaf(va.w, vb.w, acc[3][3]);
    }
    __syncthreads();
  }

  szred[srow][c] = szpart;
  float* out = zzp + (size_t)blockIdx.x * ZZW;
#pragma unroll
  for (int i = 0; i < 4; ++i)
#pragma unroll
    for (int j = 0; j < 4; ++j)
      out[(R * 4 + i) * 64 + (C * 4 + j)] = acc[i][j];
  __syncthreads();
  if (tid < 64)
    out[4096 + tid] = szred[0][tid] + szred[1][tid] + szred[2][tid] + szred[3][tid];
}

// ---------------------------------------------------------------------------
// K4: reduce zz partials over blocks -> double
// ---------------------------------------------------------------------------
__global__ void zzred_kernel(const float* __restrict__ zzp, double* __restrict__ zzs)
{
  int j = blockIdx.x * 256 + threadIdx.x;
  if (j < ZZW) {
    double s = 0;
    for (int b = 0; b < NBLK_ZZ; ++b) s += (double)zzp[(size_t)b * ZZW + j];
    zzs[j] = s;
  }
}

// ---------------------------------------------------------------------------
// K5: stats2 — BN2 stats via quadratic form (128 blocks = one per channel, 64 thr)
// ---------------------------------------------------------------------------
__global__ void stats2_kernel(const double* __restrict__ zzs,
                              const float* __restrict__ W2, const float* __restrict__ b2,
                              const float* __restrict__ g2, const float* __restrict__ be2,
                              float* __restrict__ s2out)
{
  int d = blockIdx.x;
  int c = threadIdx.x;  // 0..63
  double w_c = (double)W2[(size_t)d * 64 + c];
  double h = 0;
  for (int c2 = 0; c2 < 64; ++c2)
    h += (double)W2[(size_t)d * 64 + c2] * zzs[c * 64 + c2];
  double quad = w_c * h;                 // contribution to w^T M w
  double dz = w_c * zzs[4096 + c];       // contribution to w . sum_z
#pragma unroll
  for (int o = 32; o >= 1; o >>= 1) {
    quad += __shfl_down(quad, o, 64);
    dz += __shfl_down(dz, o, 64);
  }
  if (c == 0) {
    double S = (double)SAMP, b = (double)b2[d];
    double mean = dz / S + b;
    double Ey2 = (quad + 2.0 * b * dz) / S + b * b;
    double var = Ey2 - mean * mean;
    double sc = (double)g2[d] / sqrt(var + 1e-5);
    s2out[d] = (float)sc;
    s2out[128 + d] = (float)((double)be2[d] - mean * sc);
  }
}

// ---------------------------------------------------------------------------
// K6: output pass — recompute z1, y2 = W2 z + b2, BN2+ReLU, write 256 MB.
// 2048 blocks x 256 threads; 256 samples/block, 8 samples per barrier round.
// ---------------------------------------------------------------------------
__global__ __launch_bounds__(256) void out_kernel(const float4* __restrict__ G,
                                                  const float* __restrict__ W1,
                                                  const float* __restrict__ b1,
                                                  const float* __restrict__ s1,
                                                  const float* __restrict__ W2,
                                                  const float* __restrict__ b2,
                                                  const float* __restrict__ s2,
                                                  float* __restrict__ out)
{
  __shared__ float zt[8][64];
  const int tid = threadIdx.x;
  const int d = tid & 127;
  const int gh = tid >> 7;          // 0/1

  float w2r[64];
#pragma unroll
  for (int c = 0; c < 64; c += 4) {
    float4 v = *(const float4*)&W2[(size_t)d * 64 + c];
    w2r[c] = v.x; w2r[c + 1] = v.y; w2r[c + 2] = v.z; w2r[c + 3] = v.w;
  }
  const float sc2 = s2[d], sh2 = s2[128 + d], bb2 = b2[d];

  const int zc = tid & 63, zr = tid >> 6;    // z-staging duty
  const float w1x = W1[zc * 3 + 0], w1y = W1[zc * 3 + 1], w1z = W1[zc * 3 + 2];
  const float bb1 = b1[zc], sc1 = s1[zc], sh1 = s1[64 + zc];

  const size_t sbase = (size_t)blockIdx.x * 256;
  for (int it = 0; it < 32; ++it) {
    size_t s0 = sbase + (size_t)it * 8;
#pragma unroll
    for (int k = 0; k < 2; ++k) {
      int sl = zr + k * 4;
      float4 g = G[s0 + sl];
      float y = fmaf(w1z, g.z, fmaf(w1y, g.y, fmaf(w1x, g.x, bb1)));
      zt[sl][zc] = fmaxf(fmaf(sc1, y, sh1), 0.0f);
    }
    __syncthreads();
#pragma unroll
    for (int k = 0; k < 4; ++k) {
      int sl = gh + k * 2;
      float y2 = bb2;
#pragma unroll
      for (int c = 0; c < 64; c += 4) {
        float4 zv = *(const float4*)&zt[sl][c];
        y2 = fmaf(w2r[c], zv.x, fmaf(w2r[c + 1], zv.y,
             fmaf(w2r[c + 2], zv.z, fmaf(w2r[c + 3], zv.w, y2))));
      }
      out[(size_t)(s0 + sl) * 128 + d] = fmaxf(fmaf(sc2, y2, sh2), 0.0f);
    }
    __syncthreads();
  }
}

// ---------------------------------------------------------------------------
extern "C" void kernel_launch(void* const* d_in, const int* in_sizes, int n_in,
                              void* d_out, int out_size, void* d_ws, size_t ws_size,
                              hipStream_t stream)
{
  const float* points  = (const float*)d_in[0];
  const float* queries = (const float*)d_in[1];
  const float* W1      = (const float*)d_in[2];
  const float* b1      = (const float*)d_in[3];
  const float* gamma1  = (const float*)d_in[4];
  const float* beta1   = (const float*)d_in[5];
  const float* W2      = (const float*)d_in[6];
  const float* b2      = (const float*)d_in[7];
  const float* gamma2  = (const float*)d_in[8];
  const float* beta2   = (const float*)d_in[9];

  char* ws = (char*)d_ws;
  float4* G    = (float4*)(ws + OFF_G);
  float*  gmom = (float*)(ws + OFF_GMOM);
  float*  s1   = (float*)(ws + OFF_S1);
  float*  zzp  = (float*)(ws + OFF_ZZP);
  double* zzs  = (double*)(ws + OFF_ZZS);
  float*  s2   = (float*)(ws + OFF_S2);
  float*  out  = (float*)d_out;

  knn_kernel<<<256, 256, 0, stream>>>(points, queries, G, gmom);
  stats1_kernel<<<1, 64, 0, stream>>>(gmom, W1, b1, gamma1, beta1, s1);
  zmom_kernel<<<NBLK_ZZ, 256, 0, stream>>>(G, W1, b1, s1, zzp);
  zzred_kernel<<<17, 256, 0, stream>>>(zzp, zzs);
  stats2_kernel<<<128, 64, 0, stream>>>(zzs, W2, b2, gamma2, beta2, s2);
  out_kernel<<<2048, 256, 0, stream>>>(G, W1, b1, s1, W2, b2, s2, out);
}

// Round 2
// 456.709 us; speedup vs baseline: 2.3948x; 2.3948x over previous
//
#include <hip/hip_runtime.h>
#include <cmath>

// Problem constants
constexpr int BB = 4, LL = 8, NPTS = 4096, MQ = 1024, KNNK = 16;
constexpr int C1 = 64, C2 = 128;
constexpr int NSLICE = BB * LL;                       // 32
constexpr long long SAMP = (long long)NSLICE * MQ * KNNK;  // 524288 samples
constexpr int NBLK_ZZ = 512;
constexpr int ZZW = C1 * C1 + C1;                     // 4160 (full 64x64 + sum_z)

// Workspace layout (bytes)
constexpr size_t OFF_G    = 0;                                   // float4[SAMP] = 8 MB
constexpr size_t OFF_GMOM = (size_t)8 * 1024 * 1024;             // float[256*9]
constexpr size_t OFF_S1   = OFF_GMOM + 16384;                    // float[128]: scale1,shift1
constexpr size_t OFF_ZZP  = OFF_S1 + 1024;                       // float[NBLK_ZZ*ZZW]
constexpr size_t OFF_ZZS  = OFF_ZZP + (size_t)NBLK_ZZ * ZZW * 4; // double[ZZW]
constexpr size_t OFF_S2   = OFF_ZZS + (size_t)ZZW * 8;           // float[256]: scale2,shift2

// ---------------------------------------------------------------------------
// K1: per-slice KNN + gather. One query per wave; lanes 0..15 jointly hold the
// sorted top-16 (distributed sorted list). Points scanned as p = i*64 + lane,
// and the ballot candidate loop processes lanes in ascending order, so
// candidates arrive in strictly increasing point index -> stable tie handling
// with plain strict value compares (lower index wins ties, matching
// jax.lax.top_k). d2 arithmetic replicates the reference: p2/q2 plain (no
// fma), pq fma-chain, d = fma(-2,pq,q2+p2) (== (q2+p2)-2*pq exactly).
// Grid: 512 blocks x 1024 threads (16 waves); block covers 64 queries
// (4/wave); 64KB LDS -> 2 blocks/CU -> 32 waves/CU.
// ---------------------------------------------------------------------------
__global__ __launch_bounds__(1024, 8) void knn_kernel(const float* __restrict__ pts,
                                                      const float* __restrict__ qrs,
                                                      float4* __restrict__ G)
{
#pragma clang fp contract(off)
  __shared__ float4 sp[NPTS];   // (x,y,z,p2) = 64 KB
  const int tid = threadIdx.x;
  const int bl = blockIdx.x >> 4;    // slice (32)
  const int qt = blockIdx.x & 15;    // 16 query tiles of 64
  const int wave = tid >> 6;
  const int lane = tid & 63;

  const float* pb = pts + (size_t)bl * NPTS * 3;
  for (int p = tid; p < NPTS; p += 1024) {
    float x = pb[p * 3 + 0], y = pb[p * 3 + 1], z = pb[p * 3 + 2];
    float pp = (x * x + y * y) + z * z;       // plain rounding
    sp[p] = make_float4(x, y, z, pp);
  }
  __syncthreads();

  for (int qq = 0; qq < 4; ++qq) {
    const int q = qt * 64 + wave * 4 + qq;
    const float* qp = qrs + ((size_t)bl * MQ + q) * 3;
    const float qx = qp[0], qy = qp[1], qz = qp[2];
    const float q2 = (qx * qx + qy * qy) + qz * qz;   // plain rounding

    float Ld = 3.402823466e38f;   // lanes 0..15: sorted list values
    int   Li = 0;
    float tau = 3.402823466e38f;  // current 16th smallest (wave-uniform)

    for (int i = 0; i < 64; ++i) {
      float4 P = sp[i * 64 + lane];
      float pq = fmaf(P.z, qz, fmaf(P.y, qy, P.x * qx));
      float t = q2 + P.w;
      float d = fmaf(-2.0f, pq, t);

      unsigned long long m = __ballot(d < tau);
      while (m) {
        int b = (int)__builtin_ctzll(m);
        m &= m - 1;
        float db = __shfl(d, b, 64);
        if (db < tau) {                       // wave-uniform recheck
          int ib = i * 64 + b;
          float pd = __shfl_up(Ld, 1, 64);
          int   pi = __shfl_up(Li, 1, 64);
          if (lane == 0) pd = -3.402823466e38f;
          bool gt  = Ld > db;                 // strict: equals keep rank (lower idx first)
          bool gtp = pd > db;
          Ld = gt ? (gtp ? pd : db) : Ld;
          Li = gt ? (gtp ? pi : ib) : Li;
          tau = __shfl(Ld, 15, 64);
        }
      }
    }

    if (lane < 16) {
      float4 P = sp[Li];
      G[((size_t)bl * MQ + q) * KNNK + lane] = make_float4(P.x, P.y, P.z, 0.0f);
    }
  }
}

// ---------------------------------------------------------------------------
// K1b: coordinate moments from G (256 blocks x 256 threads, 8 samples/thread)
// ---------------------------------------------------------------------------
__global__ __launch_bounds__(256) void gmom_kernel(const float4* __restrict__ G,
                                                   float* __restrict__ gmom)
{
  __shared__ float sr[256 * 9];
  const int tid = threadIdx.x;
  float s[9];
#pragma unroll
  for (int j = 0; j < 9; ++j) s[j] = 0.0f;
  size_t base = (size_t)blockIdx.x * 2048 + tid;
#pragma unroll
  for (int k = 0; k < 8; ++k) {
    float4 P = G[base + (size_t)k * 256];
    s[0] += P.x; s[1] += P.y; s[2] += P.z;
    s[3] = fmaf(P.x, P.x, s[3]); s[4] = fmaf(P.y, P.y, s[4]); s[5] = fmaf(P.z, P.z, s[5]);
    s[6] = fmaf(P.x, P.y, s[6]); s[7] = fmaf(P.x, P.z, s[7]); s[8] = fmaf(P.y, P.z, s[8]);
  }
#pragma unroll
  for (int j = 0; j < 9; ++j) sr[tid * 9 + j] = s[j];
  __syncthreads();
  if (tid < 9) {
    float acc = 0;
    for (int r = 0; r < 256; ++r) acc += sr[r * 9 + tid];
    gmom[blockIdx.x * 9 + tid] = acc;
  }
}

// ---------------------------------------------------------------------------
// K2: stats1 — analytic BN1 stats from coord moments (1 block, 64 threads)
// ---------------------------------------------------------------------------
__global__ void stats1_kernel(const float* __restrict__ gmom,
                              const float* __restrict__ W1, const float* __restrict__ b1,
                              const float* __restrict__ g1, const float* __restrict__ be1,
                              float* __restrict__ s1out)
{
  __shared__ double m[9];
  if (threadIdx.x < 9) {
    double s = 0;
    for (int r = 0; r < 256; ++r) s += (double)gmom[r * 9 + threadIdx.x];
    m[threadIdx.x] = s / (double)SAMP;
  }
  __syncthreads();
  int c = threadIdx.x;  // 0..63
  double Ex = m[0], Ey = m[1], Ez = m[2];
  double Exx = m[3], Eyy = m[4], Ezz = m[5], Exy = m[6], Exz = m[7], Eyz = m[8];
  double wx = W1[c * 3 + 0], wy = W1[c * 3 + 1], wz = W1[c * 3 + 2], b = b1[c];
  double dot = wx * Ex + wy * Ey + wz * Ez;
  double mean = dot + b;
  double Ey2 = wx * wx * Exx + wy * wy * Eyy + wz * wz * Ezz
             + 2.0 * (wx * wy * Exy + wx * wz * Exz + wy * wz * Eyz)
             + 2.0 * b * dot + b * b;
  double var = Ey2 - mean * mean;
  double sc = (double)g1[c] / sqrt(var + 1e-5);
  s1out[c] = (float)sc;
  s1out[64 + c] = (float)((double)be1[c] - mean * sc);
}

// ---------------------------------------------------------------------------
// K3: z moments — recompute z1 from G, accumulate sum_z (64) and sum z z^T (64x64)
// 512 blocks x 256 threads, each block owns 1024 samples (8 tiles of 128).
// ---------------------------------------------------------------------------
__global__ __launch_bounds__(256) void zmom_kernel(const float4* __restrict__ G,
                                                   const float* __restrict__ W1,
                                                   const float* __restrict__ b1,
                                                   const float* __restrict__ s1,
                                                   float* __restrict__ zzp)
{
  __shared__ float zt[128][68];     // rows 16B-aligned
  __shared__ float szred[4][64];

  const int tid = threadIdx.x;
  const int c = tid & 63;
  const int srow = tid >> 6;
  const float w1x = W1[c * 3 + 0], w1y = W1[c * 3 + 1], w1z = W1[c * 3 + 2];
  const float bb = b1[c], sc = s1[c], sh = s1[64 + c];

  const int R = tid >> 4;
  const int C = tid & 15;
  float acc[4][4];
#pragma unroll
  for (int i = 0; i < 4; ++i)
#pragma unroll
    for (int j = 0; j < 4; ++j) acc[i][j] = 0.0f;
  float szpart = 0.0f;

  const size_t sbase = (size_t)blockIdx.x * 1024;
  for (int t = 0; t < 8; ++t) {
    size_t s0 = sbase + (size_t)t * 128;
#pragma unroll 4
    for (int k = 0; k < 32; ++k) {
      int sl = srow + k * 4;
      float4 g = G[s0 + sl];
      float y = fmaf(w1z, g.z, fmaf(w1y, g.y, fmaf(w1x, g.x, bb)));
      float z = fmaxf(fmaf(sc, y, sh), 0.0f);
      zt[sl][c] = z;
      szpart += z;
    }
    __syncthreads();
#pragma unroll 4
    for (int s = 0; s < 128; ++s) {
      float4 va = *(const float4*)&zt[s][R * 4];
      float4 vb = *(const float4*)&zt[s][C * 4];
      acc[0][0] = fmaf(va.x, vb.x, acc[0][0]); acc[0][1] = fmaf(va.x, vb.y, acc[0][1]);
      acc[0][2] = fmaf(va.x, vb.z, acc[0][2]); acc[0][3] = fmaf(va.x, vb.w, acc[0][3]);
      acc[1][0] = fmaf(va.y, vb.x, acc[1][0]); acc[1][1] = fmaf(va.y, vb.y, acc[1][1]);
      acc[1][2] = fmaf(va.y, vb.z, acc[1][2]); acc[1][3] = fmaf(va.y, vb.w, acc[1][3]);
      acc[2][0] = fmaf(va.z, vb.x, acc[2][0]); acc[2][1] = fmaf(va.z, vb.y, acc[2][1]);
      acc[2][2] = fmaf(va.z, vb.z, acc[2][2]); acc[2][3] = fmaf(va.z, vb.w, acc[2][3]);
      acc[3][0] = fmaf(va.w, vb.x, acc[3][0]); acc[3][1] = fmaf(va.w, vb.y, acc[3][1]);
      acc[3][2] = fmaf(va.w, vb.z, acc[3][2]); acc[3][3] = fmaf(va.w, vb.w, acc[3][3]);
    }
    __syncthreads();
  }

  szred[srow][c] = szpart;
  float* out = zzp + (size_t)blockIdx.x * ZZW;
#pragma unroll
  for (int i = 0; i < 4; ++i)
#pragma unroll
    for (int j = 0; j < 4; ++j)
      out[(R * 4 + i) * 64 + (C * 4 + j)] = acc[i][j];
  __syncthreads();
  if (tid < 64)
    out[4096 + tid] = szred[0][tid] + szred[1][tid] + szred[2][tid] + szred[3][tid];
}

// ---------------------------------------------------------------------------
// K4: reduce zz partials over blocks -> double
// ---------------------------------------------------------------------------
__global__ void zzred_kernel(const float* __restrict__ zzp, double* __restrict__ zzs)
{
  int j = blockIdx.x * 256 + threadIdx.x;
  if (j < ZZW) {
    double s = 0;
    for (int b = 0; b < NBLK_ZZ; ++b) s += (double)zzp[(size_t)b * ZZW + j];
    zzs[j] = s;
  }
}

// ---------------------------------------------------------------------------
// K5: stats2 — BN2 stats via quadratic form (128 blocks = one per channel, 64 thr)
// ---------------------------------------------------------------------------
__global__ void stats2_kernel(const double* __restrict__ zzs,
                              const float* __restrict__ W2, const float* __restrict__ b2,
                              const float* __restrict__ g2, const float* __restrict__ be2,
                              float* __restrict__ s2out)
{
  int d = blockIdx.x;
  int c = threadIdx.x;  // 0..63
  double w_c = (double)W2[(size_t)d * 64 + c];
  double h = 0;
  for (int c2 = 0; c2 < 64; ++c2)
    h += (double)W2[(size_t)d * 64 + c2] * zzs[c * 64 + c2];
  double quad = w_c * h;
  double dz = w_c * zzs[4096 + c];
#pragma unroll
  for (int o = 32; o >= 1; o >>= 1) {
    quad += __shfl_down(quad, o, 64);
    dz += __shfl_down(dz, o, 64);
  }
  if (c == 0) {
    double S = (double)SAMP, b = (double)b2[d];
    double mean = dz / S + b;
    double Ey2 = (quad + 2.0 * b * dz) / S + b * b;
    double var = Ey2 - mean * mean;
    double sc = (double)g2[d] / sqrt(var + 1e-5);
    s2out[d] = (float)sc;
    s2out[128 + d] = (float)((double)be2[d] - mean * sc);
  }
}

// ---------------------------------------------------------------------------
// K6: output pass — recompute z1, y2 = W2 z + b2, BN2+ReLU, write 256 MB.
// 2048 blocks x 256 threads; 256 samples/block, 8 samples per barrier round.
// ---------------------------------------------------------------------------
__global__ __launch_bounds__(256) void out_kernel(const float4* __restrict__ G,
                                                  const float* __restrict__ W1,
                                                  const float* __restrict__ b1,
                                                  const float* __restrict__ s1,
                                                  const float* __restrict__ W2,
                                                  const float* __restrict__ b2,
                                                  const float* __restrict__ s2,
                                                  float* __restrict__ out)
{
  __shared__ float zt[8][64];
  const int tid = threadIdx.x;
  const int d = tid & 127;
  const int gh = tid >> 7;          // 0/1

  float w2r[64];
#pragma unroll
  for (int c = 0; c < 64; c += 4) {
    float4 v = *(const float4*)&W2[(size_t)d * 64 + c];
    w2r[c] = v.x; w2r[c + 1] = v.y; w2r[c + 2] = v.z; w2r[c + 3] = v.w;
  }
  const float sc2 = s2[d], sh2 = s2[128 + d], bb2 = b2[d];

  const int zc = tid & 63, zr = tid >> 6;
  const float w1x = W1[zc * 3 + 0], w1y = W1[zc * 3 + 1], w1z = W1[zc * 3 + 2];
  const float bb1 = b1[zc], sc1 = s1[zc], sh1 = s1[64 + zc];

  const size_t sbase = (size_t)blockIdx.x * 256;
  for (int it = 0; it < 32; ++it) {
    size_t s0 = sbase + (size_t)it * 8;
#pragma unroll
    for (int k = 0; k < 2; ++k) {
      int sl = zr + k * 4;
      float4 g = G[s0 + sl];
      float y = fmaf(w1z, g.z, fmaf(w1y, g.y, fmaf(w1x, g.x, bb1)));
      zt[sl][zc] = fmaxf(fmaf(sc1, y, sh1), 0.0f);
    }
    __syncthreads();
#pragma unroll
    for (int k = 0; k < 4; ++k) {
      int sl = gh + k * 2;
      float y2 = bb2;
#pragma unroll
      for (int c = 0; c < 64; c += 4) {
        float4 zv = *(const float4*)&zt[sl][c];
        y2 = fmaf(w2r[c], zv.x, fmaf(w2r[c + 1], zv.y,
             fmaf(w2r[c + 2], zv.z, fmaf(w2r[c + 3], zv.w, y2))));
      }
      out[(size_t)(s0 + sl) * 128 + d] = fmaxf(fmaf(sc2, y2, sh2), 0.0f);
    }
    __syncthreads();
  }
}

// ---------------------------------------------------------------------------
extern "C" void kernel_launch(void* const* d_in, const int* in_sizes, int n_in,
                              void* d_out, int out_size, void* d_ws, size_t ws_size,
                              hipStream_t stream)
{
  const float* points  = (const float*)d_in[0];
  const float* queries = (const float*)d_in[1];
  const float* W1      = (const float*)d_in[2];
  const float* b1      = (const float*)d_in[3];
  const float* gamma1  = (const float*)d_in[4];
  const float* beta1   = (const float*)d_in[5];
  const float* W2      = (const float*)d_in[6];
  const float* b2      = (const float*)d_in[7];
  const float* gamma2  = (const float*)d_in[8];
  const float* beta2   = (const float*)d_in[9];

  char* ws = (char*)d_ws;
  float4* G    = (float4*)(ws + OFF_G);
  float*  gmom = (float*)(ws + OFF_GMOM);
  float*  s1   = (float*)(ws + OFF_S1);
  float*  zzp  = (float*)(ws + OFF_ZZP);
  double* zzs  = (double*)(ws + OFF_ZZS);
  float*  s2   = (float*)(ws + OFF_S2);
  float*  out  = (float*)d_out;

  knn_kernel<<<512, 1024, 0, stream>>>(points, queries, G);
  gmom_kernel<<<256, 256, 0, stream>>>(G, gmom);
  stats1_kernel<<<1, 64, 0, stream>>>(gmom, W1, b1, gamma1, beta1, s1);
  zmom_kernel<<<NBLK_ZZ, 256, 0, stream>>>(G, W1, b1, s1, zzp);
  zzred_kernel<<<17, 256, 0, stream>>>(zzp, zzs);
  stats2_kernel<<<128, 64, 0, stream>>>(zzs, W2, b2, gamma2, beta2, s2);
  out_kernel<<<2048, 256, 0, stream>>>(G, W1, b1, s1, W2, b2, s2, out);
}

// Round 3
// 395.664 us; speedup vs baseline: 2.7643x; 1.1543x over previous
//
#include <hip/hip_runtime.h>
#include <cmath>

// Problem constants
constexpr int BB = 4, LL = 8, NPTS = 4096, MQ = 1024, KNNK = 16;
constexpr int C1 = 64, C2 = 128;
constexpr int NSLICE = BB * LL;                       // 32
constexpr long long SAMP = (long long)NSLICE * MQ * KNNK;  // 524288 samples
constexpr int NBLK_ZZ = 512;
constexpr int ZZW = C1 * C1 + C1;                     // 4160 (full 64x64 + sum_z)

// Workspace layout (bytes)
constexpr size_t OFF_G    = 0;                                   // float4[SAMP] = 8 MB
constexpr size_t OFF_GMOM = (size_t)8 * 1024 * 1024;             // float[256*9]
constexpr size_t OFF_S1   = OFF_GMOM + 16384;                    // float[128]: scale1,shift1
constexpr size_t OFF_ZZP  = OFF_S1 + 1024;                       // float[NBLK_ZZ*ZZW]
constexpr size_t OFF_ZZS  = OFF_ZZP + (size_t)NBLK_ZZ * ZZW * 4; // double[ZZW]
constexpr size_t OFF_S2   = OFF_ZZS + (size_t)ZZW * 8;           // float[256]: scale2,shift2

// ---------------------------------------------------------------------------
// K1: per-slice KNN + gather. One wave serves FOUR queries simultaneously:
// the wave is split into 4 segments of 16 lanes; segment s holds query s's
// sorted top-16 as a distributed list. Each scan iteration i loads one point
// per lane (p = i*64+lane) and computes 4 distances (one per query). Ballot
// masks per query; the insert loop pops one candidate per query per round and
// performs ONE wave-wide shift-insert serving all 4 segments (pd forced to
// -inf at segment heads). Candidates are processed in ascending point index
// per query (ctz order within i, i ascending), so strict value compares give
// lower-index-first on ties, matching jax.lax.top_k. A candidate that is
// stale (>= current 16th) inserts as a no-op (strict compares), so no
// recheck is needed. d2 arithmetic replicates the reference: p2/q2 plain (no
// fma), pq fma-chain, d = fma(-2,pq,q2+p2) (== (q2+p2)-2*pq exactly).
// Grid: 512 blocks x 1024 threads (16 waves); block covers 64 queries
// (4/wave); 64KB LDS -> 2 blocks/CU -> 32 waves/CU.
// ---------------------------------------------------------------------------
__global__ __launch_bounds__(1024, 8) void knn_kernel(const float* __restrict__ pts,
                                                      const float* __restrict__ qrs,
                                                      float4* __restrict__ G)
{
#pragma clang fp contract(off)
  __shared__ float4 sp[NPTS];   // (x,y,z,p2) = 64 KB
  const int tid = threadIdx.x;
  const int bl = blockIdx.x >> 4;    // slice (32)
  const int qt = blockIdx.x & 15;    // 16 query tiles of 64
  const int wave = tid >> 6;
  const int lane = tid & 63;
  const float INF = 3.402823466e38f;

  const float* pb = pts + (size_t)bl * NPTS * 3;
  for (int p = tid; p < NPTS; p += 1024) {
    float x = pb[p * 3 + 0], y = pb[p * 3 + 1], z = pb[p * 3 + 2];
    float pp = (x * x + y * y) + z * z;       // plain rounding
    sp[p] = make_float4(x, y, z, pp);
  }
  __syncthreads();

  const int qbase = qt * 64 + wave * 4;
  const float* qp = qrs + ((size_t)bl * MQ + qbase) * 3;
  // 4 queries' coords (wave-uniform)
  const float qxA = qp[0], qyA = qp[1], qzA = qp[2];
  const float qxB = qp[3], qyB = qp[4], qzB = qp[5];
  const float qxC = qp[6], qyC = qp[7], qzC = qp[8];
  const float qxD = qp[9], qyD = qp[10], qzD = qp[11];
  const float q2A = (qxA * qxA + qyA * qyA) + qzA * qzA;   // plain rounding
  const float q2B = (qxB * qxB + qyB * qyB) + qzB * qzB;
  const float q2C = (qxC * qxC + qyC * qyC) + qzC * qzC;
  const float q2D = (qxD * qxD + qyD * qyD) + qzD * qzD;

  float Ld = INF;     // segmented sorted lists (4 segments of 16 lanes)
  int   Li = 0;
  float tauA = INF, tauB = INF, tauC = INF, tauD = INF;
  const int seg = lane >> 4;
  const bool segHead = (lane & 15) == 0;

  for (int i = 0; i < 64; ++i) {
    float4 P = sp[i * 64 + lane];
    float pqA = fmaf(P.z, qzA, fmaf(P.y, qyA, P.x * qxA));
    float pqB = fmaf(P.z, qzB, fmaf(P.y, qyB, P.x * qxB));
    float pqC = fmaf(P.z, qzC, fmaf(P.y, qyC, P.x * qxC));
    float pqD = fmaf(P.z, qzD, fmaf(P.y, qyD, P.x * qxD));
    float dA = fmaf(-2.0f, pqA, q2A + P.w);
    float dB = fmaf(-2.0f, pqB, q2B + P.w);
    float dC = fmaf(-2.0f, pqC, q2C + P.w);
    float dD = fmaf(-2.0f, pqD, q2D + P.w);

    unsigned long long mA = __ballot(dA < tauA);
    unsigned long long mB = __ballot(dB < tauB);
    unsigned long long mC = __ballot(dC < tauC);
    unsigned long long mD = __ballot(dD < tauD);

    if (mA | mB | mC | mD) {
      do {
        float vA = INF, vB = INF, vC = INF, vD = INF;
        int iA = 0, iB = 0, iC = 0, iD = 0;
        if (mA) { int b = (int)__builtin_ctzll(mA); mA &= mA - 1;
                  vA = __shfl(dA, b, 64); iA = i * 64 + b; }
        if (mB) { int b = (int)__builtin_ctzll(mB); mB &= mB - 1;
                  vB = __shfl(dB, b, 64); iB = i * 64 + b; }
        if (mC) { int b = (int)__builtin_ctzll(mC); mC &= mC - 1;
                  vC = __shfl(dC, b, 64); iC = i * 64 + b; }
        if (mD) { int b = (int)__builtin_ctzll(mD); mD &= mD - 1;
                  vD = __shfl(dD, b, 64); iD = i * 64 + b; }
        // per-lane segment select of (v, vi)
        float v0 = (seg & 1) ? vB : vA;
        float v1 = (seg & 1) ? vD : vC;
        float v  = (seg & 2) ? v1 : v0;
        int  i0 = (seg & 1) ? iB : iA;
        int  i1 = (seg & 1) ? iD : iC;
        int  vi = (seg & 2) ? i1 : i0;
        // one wave-wide shift-insert serving all 4 segments
        float pd = __shfl_up(Ld, 1, 64);
        int   pi = __shfl_up(Li, 1, 64);
        if (segHead) pd = -INF;
        bool gt  = Ld > v;     // strict: equals keep rank (lower idx first)
        bool gtp = pd > v;
        Ld = gt ? (gtp ? pd : v) : Ld;
        Li = gt ? (gtp ? pi : vi) : Li;
      } while (mA | mB | mC | mD);
      tauA = __shfl(Ld, 15, 64);
      tauB = __shfl(Ld, 31, 64);
      tauC = __shfl(Ld, 47, 64);
      tauD = __shfl(Ld, 63, 64);
    }
  }

  // gather write: each lane writes one neighbor (query = qbase+seg, rank = lane&15)
  float4 P = sp[Li];
  G[((size_t)bl * MQ + qbase + seg) * KNNK + (lane & 15)] =
      make_float4(P.x, P.y, P.z, 0.0f);
}

// ---------------------------------------------------------------------------
// K1b: coordinate moments from G (256 blocks x 256 threads, 8 samples/thread)
// ---------------------------------------------------------------------------
__global__ __launch_bounds__(256) void gmom_kernel(const float4* __restrict__ G,
                                                   float* __restrict__ gmom)
{
  __shared__ float sr[256 * 9];
  const int tid = threadIdx.x;
  float s[9];
#pragma unroll
  for (int j = 0; j < 9; ++j) s[j] = 0.0f;
  size_t base = (size_t)blockIdx.x * 2048 + tid;
#pragma unroll
  for (int k = 0; k < 8; ++k) {
    float4 P = G[base + (size_t)k * 256];
    s[0] += P.x; s[1] += P.y; s[2] += P.z;
    s[3] = fmaf(P.x, P.x, s[3]); s[4] = fmaf(P.y, P.y, s[4]); s[5] = fmaf(P.z, P.z, s[5]);
    s[6] = fmaf(P.x, P.y, s[6]); s[7] = fmaf(P.x, P.z, s[7]); s[8] = fmaf(P.y, P.z, s[8]);
  }
#pragma unroll
  for (int j = 0; j < 9; ++j) sr[tid * 9 + j] = s[j];
  __syncthreads();
  if (tid < 9) {
    float acc = 0;
    for (int r = 0; r < 256; ++r) acc += sr[r * 9 + tid];
    gmom[blockIdx.x * 9 + tid] = acc;
  }
}

// ---------------------------------------------------------------------------
// K2: stats1 — analytic BN1 stats from coord moments (1 block, 64 threads)
// ---------------------------------------------------------------------------
__global__ void stats1_kernel(const float* __restrict__ gmom,
                              const float* __restrict__ W1, const float* __restrict__ b1,
                              const float* __restrict__ g1, const float* __restrict__ be1,
                              float* __restrict__ s1out)
{
  __shared__ double m[9];
  if (threadIdx.x < 9) {
    double s = 0;
    for (int r = 0; r < 256; ++r) s += (double)gmom[r * 9 + threadIdx.x];
    m[threadIdx.x] = s / (double)SAMP;
  }
  __syncthreads();
  int c = threadIdx.x;  // 0..63
  double Ex = m[0], Ey = m[1], Ez = m[2];
  double Exx = m[3], Eyy = m[4], Ezz = m[5], Exy = m[6], Exz = m[7], Eyz = m[8];
  double wx = W1[c * 3 + 0], wy = W1[c * 3 + 1], wz = W1[c * 3 + 2], b = b1[c];
  double dot = wx * Ex + wy * Ey + wz * Ez;
  double mean = dot + b;
  double Ey2 = wx * wx * Exx + wy * wy * Eyy + wz * wz * Ezz
             + 2.0 * (wx * wy * Exy + wx * wz * Exz + wy * wz * Eyz)
             + 2.0 * b * dot + b * b;
  double var = Ey2 - mean * mean;
  double sc = (double)g1[c] / sqrt(var + 1e-5);
  s1out[c] = (float)sc;
  s1out[64 + c] = (float)((double)be1[c] - mean * sc);
}

// ---------------------------------------------------------------------------
// K3: z moments — recompute z1 from G, accumulate sum_z (64) and sum z z^T (64x64)
// 512 blocks x 256 threads, each block owns 1024 samples (8 tiles of 128).
// ---------------------------------------------------------------------------
__global__ __launch_bounds__(256) void zmom_kernel(const float4* __restrict__ G,
                                                   const float* __restrict__ W1,
                                                   const float* __restrict__ b1,
                                                   const float* __restrict__ s1,
                                                   float* __restrict__ zzp)
{
  __shared__ float zt[128][68];     // rows 16B-aligned
  __shared__ float szred[4][64];

  const int tid = threadIdx.x;
  const int c = tid & 63;
  const int srow = tid >> 6;
  const float w1x = W1[c * 3 + 0], w1y = W1[c * 3 + 1], w1z = W1[c * 3 + 2];
  const float bb = b1[c], sc = s1[c], sh = s1[64 + c];

  const int R = tid >> 4;
  const int C = tid & 15;
  float acc[4][4];
#pragma unroll
  for (int i = 0; i < 4; ++i)
#pragma unroll
    for (int j = 0; j < 4; ++j) acc[i][j] = 0.0f;
  float szpart = 0.0f;

  const size_t sbase = (size_t)blockIdx.x * 1024;
  for (int t = 0; t < 8; ++t) {
    size_t s0 = sbase + (size_t)t * 128;
#pragma unroll 4
    for (int k = 0; k < 32; ++k) {
      int sl = srow + k * 4;
      float4 g = G[s0 + sl];
      float y = fmaf(w1z, g.z, fmaf(w1y, g.y, fmaf(w1x, g.x, bb)));
      float z = fmaxf(fmaf(sc, y, sh), 0.0f);
      zt[sl][c] = z;
      szpart += z;
    }
    __syncthreads();
#pragma unroll 4
    for (int s = 0; s < 128; ++s) {
      float4 va = *(const float4*)&zt[s][R * 4];
      float4 vb = *(const float4*)&zt[s][C * 4];
      acc[0][0] = fmaf(va.x, vb.x, acc[0][0]); acc[0][1] = fmaf(va.x, vb.y, acc[0][1]);
      acc[0][2] = fmaf(va.x, vb.z, acc[0][2]); acc[0][3] = fmaf(va.x, vb.w, acc[0][3]);
      acc[1][0] = fmaf(va.y, vb.x, acc[1][0]); acc[1][1] = fmaf(va.y, vb.y, acc[1][1]);
      acc[1][2] = fmaf(va.y, vb.z, acc[1][2]); acc[1][3] = fmaf(va.y, vb.w, acc[1][3]);
      acc[2][0] = fmaf(va.z, vb.x, acc[2][0]); acc[2][1] = fmaf(va.z, vb.y, acc[2][1]);
      acc[2][2] = fmaf(va.z, vb.z, acc[2][2]); acc[2][3] = fmaf(va.z, vb.w, acc[2][3]);
      acc[3][0] = fmaf(va.w, vb.x, acc[3][0]); acc[3][1] = fmaf(va.w, vb.y, acc[3][1]);
      acc[3][2] = fmaf(va.w, vb.z, acc[3][2]); acc[3][3] = fmaf(va.w, vb.w, acc[3][3]);
    }
    __syncthreads();
  }

  szred[srow][c] = szpart;
  float* out = zzp + (size_t)blockIdx.x * ZZW;
#pragma unroll
  for (int i = 0; i < 4; ++i)
#pragma unroll
    for (int j = 0; j < 4; ++j)
      out[(R * 4 + i) * 64 + (C * 4 + j)] = acc[i][j];
  __syncthreads();
  if (tid < 64)
    out[4096 + tid] = szred[0][tid] + szred[1][tid] + szred[2][tid] + szred[3][tid];
}

// ---------------------------------------------------------------------------
// K4: reduce zz partials over blocks -> double
// ---------------------------------------------------------------------------
__global__ void zzred_kernel(const float* __restrict__ zzp, double* __restrict__ zzs)
{
  int j = blockIdx.x * 256 + threadIdx.x;
  if (j < ZZW) {
    double s = 0;
    for (int b = 0; b < NBLK_ZZ; ++b) s += (double)zzp[(size_t)b * ZZW + j];
    zzs[j] = s;
  }
}

// ---------------------------------------------------------------------------
// K5: stats2 — BN2 stats via quadratic form (128 blocks = one per channel, 64 thr)
// ---------------------------------------------------------------------------
__global__ void stats2_kernel(const double* __restrict__ zzs,
                              const float* __restrict__ W2, const float* __restrict__ b2,
                              const float* __restrict__ g2, const float* __restrict__ be2,
                              float* __restrict__ s2out)
{
  int d = blockIdx.x;
  int c = threadIdx.x;  // 0..63
  double w_c = (double)W2[(size_t)d * 64 + c];
  double h = 0;
  for (int c2 = 0; c2 < 64; ++c2)
    h += (double)W2[(size_t)d * 64 + c2] * zzs[c * 64 + c2];
  double quad = w_c * h;
  double dz = w_c * zzs[4096 + c];
#pragma unroll
  for (int o = 32; o >= 1; o >>= 1) {
    quad += __shfl_down(quad, o, 64);
    dz += __shfl_down(dz, o, 64);
  }
  if (c == 0) {
    double S = (double)SAMP, b = (double)b2[d];
    double mean = dz / S + b;
    double Ey2 = (quad + 2.0 * b * dz) / S + b * b;
    double var = Ey2 - mean * mean;
    double sc = (double)g2[d] / sqrt(var + 1e-5);
    s2out[d] = (float)sc;
    s2out[128 + d] = (float)((double)be2[d] - mean * sc);
  }
}

// ---------------------------------------------------------------------------
// K6: output pass — recompute z1, y2 = W2 z + b2, BN2+ReLU, write 256 MB.
// 2048 blocks x 256 threads; 256 samples/block, 8 samples per barrier round.
// ---------------------------------------------------------------------------
__global__ __launch_bounds__(256) void out_kernel(const float4* __restrict__ G,
                                                  const float* __restrict__ W1,
                                                  const float* __restrict__ b1,
                                                  const float* __restrict__ s1,
                                                  const float* __restrict__ W2,
                                                  const float* __restrict__ b2,
                                                  const float* __restrict__ s2,
                                                  float* __restrict__ out)
{
  __shared__ float zt[8][64];
  const int tid = threadIdx.x;
  const int d = tid & 127;
  const int gh = tid >> 7;          // 0/1

  float w2r[64];
#pragma unroll
  for (int c = 0; c < 64; c += 4) {
    float4 v = *(const float4*)&W2[(size_t)d * 64 + c];
    w2r[c] = v.x; w2r[c + 1] = v.y; w2r[c + 2] = v.z; w2r[c + 3] = v.w;
  }
  const float sc2 = s2[d], sh2 = s2[128 + d], bb2 = b2[d];

  const int zc = tid & 63, zr = tid >> 6;
  const float w1x = W1[zc * 3 + 0], w1y = W1[zc * 3 + 1], w1z = W1[zc * 3 + 2];
  const float bb1 = b1[zc], sc1 = s1[zc], sh1 = s1[64 + zc];

  const size_t sbase = (size_t)blockIdx.x * 256;
  for (int it = 0; it < 32; ++it) {
    size_t s0 = sbase + (size_t)it * 8;
#pragma unroll
    for (int k = 0; k < 2; ++k) {
      int sl = zr + k * 4;
      float4 g = G[s0 + sl];
      float y = fmaf(w1z, g.z, fmaf(w1y, g.y, fmaf(w1x, g.x, bb1)));
      zt[sl][zc] = fmaxf(fmaf(sc1, y, sh1), 0.0f);
    }
    __syncthreads();
#pragma unroll
    for (int k = 0; k < 4; ++k) {
      int sl = gh + k * 2;
      float y2 = bb2;
#pragma unroll
      for (int c = 0; c < 64; c += 4) {
        float4 zv = *(const float4*)&zt[sl][c];
        y2 = fmaf(w2r[c], zv.x, fmaf(w2r[c + 1], zv.y,
             fmaf(w2r[c + 2], zv.z, fmaf(w2r[c + 3], zv.w, y2))));
      }
      out[(size_t)(s0 + sl) * 128 + d] = fmaxf(fmaf(sc2, y2, sh2), 0.0f);
    }
    __syncthreads();
  }
}

// ---------------------------------------------------------------------------
extern "C" void kernel_launch(void* const* d_in, const int* in_sizes, int n_in,
                              void* d_out, int out_size, void* d_ws, size_t ws_size,
                              hipStream_t stream)
{
  const float* points  = (const float*)d_in[0];
  const float* queries = (const float*)d_in[1];
  const float* W1      = (const float*)d_in[2];
  const float* b1      = (const float*)d_in[3];
  const float* gamma1  = (const float*)d_in[4];
  const float* beta1   = (const float*)d_in[5];
  const float* W2      = (const float*)d_in[6];
  const float* b2      = (const float*)d_in[7];
  const float* gamma2  = (const float*)d_in[8];
  const float* beta2   = (const float*)d_in[9];

  char* ws = (char*)d_ws;
  float4* G    = (float4*)(ws + OFF_G);
  float*  gmom = (float*)(ws + OFF_GMOM);
  float*  s1   = (float*)(ws + OFF_S1);
  float*  zzp  = (float*)(ws + OFF_ZZP);
  double* zzs  = (double*)(ws + OFF_ZZS);
  float*  s2   = (float*)(ws + OFF_S2);
  float*  out  = (float*)d_out;

  knn_kernel<<<512, 1024, 0, stream>>>(points, queries, G);
  gmom_kernel<<<256, 256, 0, stream>>>(G, gmom);
  stats1_kernel<<<1, 64, 0, stream>>>(gmom, W1, b1, gamma1, beta1, s1);
  zmom_kernel<<<NBLK_ZZ, 256, 0, stream>>>(G, W1, b1, s1, zzp);
  zzred_kernel<<<17, 256, 0, stream>>>(zzp, zzs);
  stats2_kernel<<<128, 64, 0, stream>>>(zzs, W2, b2, gamma2, beta2, s2);
  out_kernel<<<2048, 256, 0, stream>>>(G, W1, b1, s1, W2, b2, s2, out);
}

// Round 4
// 362.585 us; speedup vs baseline: 3.0165x; 1.0912x over previous
//
#include <hip/hip_runtime.h>
#include <cmath>

// Problem constants
constexpr int BB = 4, LL = 8, NPTS = 4096, MQ = 1024, KNNK = 16;
constexpr int C1 = 64, C2 = 128;
constexpr int NSLICE = BB * LL;                       // 32
constexpr long long SAMP = (long long)NSLICE * MQ * KNNK;  // 524288 samples
constexpr int NBLK_ZZ = 512;
constexpr int ZZW = C1 * C1 + C1;                     // 4160 (full 64x64 + sum_z)

// Workspace layout (bytes)
constexpr size_t OFF_G    = 0;                                   // float4[SAMP] = 8 MB
constexpr size_t OFF_GMOM = (size_t)8 * 1024 * 1024;             // float[256*9]
constexpr size_t OFF_S1   = OFF_GMOM + 16384;                    // float[128]: scale1,shift1
constexpr size_t OFF_ZZP  = OFF_S1 + 1024;                       // float[NBLK_ZZ*ZZW]
constexpr size_t OFF_ZZS  = OFF_ZZP + (size_t)NBLK_ZZ * ZZW * 4; // double[ZZW]
constexpr size_t OFF_S2   = OFF_ZZS + (size_t)ZZW * 8;           // float[256]: scale2,shift2

// ---------------------------------------------------------------------------
// K1: per-slice KNN + gather. One wave serves FOUR queries simultaneously
// (4 segments of 16 lanes, distributed sorted lists). See R2/R3 notes.
// ---------------------------------------------------------------------------
__global__ __launch_bounds__(1024, 8) void knn_kernel(const float* __restrict__ pts,
                                                      const float* __restrict__ qrs,
                                                      float4* __restrict__ G)
{
#pragma clang fp contract(off)
  __shared__ float4 sp[NPTS];   // (x,y,z,p2) = 64 KB
  const int tid = threadIdx.x;
  const int bl = blockIdx.x >> 4;    // slice (32)
  const int qt = blockIdx.x & 15;    // 16 query tiles of 64
  const int wave = tid >> 6;
  const int lane = tid & 63;
  const float INF = 3.402823466e38f;

  const float* pb = pts + (size_t)bl * NPTS * 3;
  for (int p = tid; p < NPTS; p += 1024) {
    float x = pb[p * 3 + 0], y = pb[p * 3 + 1], z = pb[p * 3 + 2];
    float pp = (x * x + y * y) + z * z;       // plain rounding
    sp[p] = make_float4(x, y, z, pp);
  }
  __syncthreads();

  const int qbase = qt * 64 + wave * 4;
  const float* qp = qrs + ((size_t)bl * MQ + qbase) * 3;
  const float qxA = qp[0], qyA = qp[1], qzA = qp[2];
  const float qxB = qp[3], qyB = qp[4], qzB = qp[5];
  const float qxC = qp[6], qyC = qp[7], qzC = qp[8];
  const float qxD = qp[9], qyD = qp[10], qzD = qp[11];
  const float q2A = (qxA * qxA + qyA * qyA) + qzA * qzA;   // plain rounding
  const float q2B = (qxB * qxB + qyB * qyB) + qzB * qzB;
  const float q2C = (qxC * qxC + qyC * qyC) + qzC * qzC;
  const float q2D = (qxD * qxD + qyD * qyD) + qzD * qzD;

  float Ld = INF;     // segmented sorted lists (4 segments of 16 lanes)
  int   Li = 0;
  float tauA = INF, tauB = INF, tauC = INF, tauD = INF;
  const int seg = lane >> 4;
  const bool segHead = (lane & 15) == 0;

  for (int i = 0; i < 64; ++i) {
    float4 P = sp[i * 64 + lane];
    float pqA = fmaf(P.z, qzA, fmaf(P.y, qyA, P.x * qxA));
    float pqB = fmaf(P.z, qzB, fmaf(P.y, qyB, P.x * qxB));
    float pqC = fmaf(P.z, qzC, fmaf(P.y, qyC, P.x * qxC));
    float pqD = fmaf(P.z, qzD, fmaf(P.y, qyD, P.x * qxD));
    float dA = fmaf(-2.0f, pqA, q2A + P.w);
    float dB = fmaf(-2.0f, pqB, q2B + P.w);
    float dC = fmaf(-2.0f, pqC, q2C + P.w);
    float dD = fmaf(-2.0f, pqD, q2D + P.w);

    unsigned long long mA = __ballot(dA < tauA);
    unsigned long long mB = __ballot(dB < tauB);
    unsigned long long mC = __ballot(dC < tauC);
    unsigned long long mD = __ballot(dD < tauD);

    if (mA | mB | mC | mD) {
      do {
        float vA = INF, vB = INF, vC = INF, vD = INF;
        int iA = 0, iB = 0, iC = 0, iD = 0;
        if (mA) { int b = (int)__builtin_ctzll(mA); mA &= mA - 1;
                  vA = __shfl(dA, b, 64); iA = i * 64 + b; }
        if (mB) { int b = (int)__builtin_ctzll(mB); mB &= mB - 1;
                  vB = __shfl(dB, b, 64); iB = i * 64 + b; }
        if (mC) { int b = (int)__builtin_ctzll(mC); mC &= mC - 1;
                  vC = __shfl(dC, b, 64); iC = i * 64 + b; }
        if (mD) { int b = (int)__builtin_ctzll(mD); mD &= mD - 1;
                  vD = __shfl(dD, b, 64); iD = i * 64 + b; }
        float v0 = (seg & 1) ? vB : vA;
        float v1 = (seg & 1) ? vD : vC;
        float v  = (seg & 2) ? v1 : v0;
        int  i0 = (seg & 1) ? iB : iA;
        int  i1 = (seg & 1) ? iD : iC;
        int  vi = (seg & 2) ? i1 : i0;
        float pd = __shfl_up(Ld, 1, 64);
        int   pi = __shfl_up(Li, 1, 64);
        if (segHead) pd = -INF;
        bool gt  = Ld > v;     // strict: equals keep rank (lower idx first)
        bool gtp = pd > v;
        Ld = gt ? (gtp ? pd : v) : Ld;
        Li = gt ? (gtp ? pi : vi) : Li;
      } while (mA | mB | mC | mD);
      tauA = __shfl(Ld, 15, 64);
      tauB = __shfl(Ld, 31, 64);
      tauC = __shfl(Ld, 47, 64);
      tauD = __shfl(Ld, 63, 64);
    }
  }

  float4 P = sp[Li];
  G[((size_t)bl * MQ + qbase + seg) * KNNK + (lane & 15)] =
      make_float4(P.x, P.y, P.z, 0.0f);
}

// ---------------------------------------------------------------------------
// K1b: coordinate moments from G (256 blocks x 256 threads, 8 samples/thread)
// ---------------------------------------------------------------------------
__global__ __launch_bounds__(256) void gmom_kernel(const float4* __restrict__ G,
                                                   float* __restrict__ gmom)
{
  __shared__ float sr[256 * 9];
  const int tid = threadIdx.x;
  float s[9];
#pragma unroll
  for (int j = 0; j < 9; ++j) s[j] = 0.0f;
  size_t base = (size_t)blockIdx.x * 2048 + tid;
#pragma unroll
  for (int k = 0; k < 8; ++k) {
    float4 P = G[base + (size_t)k * 256];
    s[0] += P.x; s[1] += P.y; s[2] += P.z;
    s[3] = fmaf(P.x, P.x, s[3]); s[4] = fmaf(P.y, P.y, s[4]); s[5] = fmaf(P.z, P.z, s[5]);
    s[6] = fmaf(P.x, P.y, s[6]); s[7] = fmaf(P.x, P.z, s[7]); s[8] = fmaf(P.y, P.z, s[8]);
  }
#pragma unroll
  for (int j = 0; j < 9; ++j) sr[tid * 9 + j] = s[j];
  __syncthreads();
  if (tid < 9) {
    float acc = 0;
    for (int r = 0; r < 256; ++r) acc += sr[r * 9 + tid];
    gmom[blockIdx.x * 9 + tid] = acc;
  }
}

// ---------------------------------------------------------------------------
// K2: stats1 — analytic BN1 stats from coord moments (1 block, 64 threads)
// ---------------------------------------------------------------------------
__global__ void stats1_kernel(const float* __restrict__ gmom,
                              const float* __restrict__ W1, const float* __restrict__ b1,
                              const float* __restrict__ g1, const float* __restrict__ be1,
                              float* __restrict__ s1out)
{
  __shared__ double m[9];
  if (threadIdx.x < 9) {
    double s = 0;
    for (int r = 0; r < 256; ++r) s += (double)gmom[r * 9 + threadIdx.x];
    m[threadIdx.x] = s / (double)SAMP;
  }
  __syncthreads();
  int c = threadIdx.x;  // 0..63
  double Ex = m[0], Ey = m[1], Ez = m[2];
  double Exx = m[3], Eyy = m[4], Ezz = m[5], Exy = m[6], Exz = m[7], Eyz = m[8];
  double wx = W1[c * 3 + 0], wy = W1[c * 3 + 1], wz = W1[c * 3 + 2], b = b1[c];
  double dot = wx * Ex + wy * Ey + wz * Ez;
  double mean = dot + b;
  double Ey2 = wx * wx * Exx + wy * wy * Eyy + wz * wz * Ezz
             + 2.0 * (wx * wy * Exy + wx * wz * Exz + wy * wz * Eyz)
             + 2.0 * b * dot + b * b;
  double var = Ey2 - mean * mean;
  double sc = (double)g1[c] / sqrt(var + 1e-5);
  s1out[c] = (float)sc;
  s1out[64 + c] = (float)((double)be1[c] - mean * sc);
}

// ---------------------------------------------------------------------------
// K3: z moments — recompute z1 from G, accumulate sum_z (64) and sum z z^T (64x64)
// ---------------------------------------------------------------------------
__global__ __launch_bounds__(256) void zmom_kernel(const float4* __restrict__ G,
                                                   const float* __restrict__ W1,
                                                   const float* __restrict__ b1,
                                                   const float* __restrict__ s1,
                                                   float* __restrict__ zzp)
{
  __shared__ float zt[128][68];     // rows 16B-aligned
  __shared__ float szred[4][64];

  const int tid = threadIdx.x;
  const int c = tid & 63;
  const int srow = tid >> 6;
  const float w1x = W1[c * 3 + 0], w1y = W1[c * 3 + 1], w1z = W1[c * 3 + 2];
  const float bb = b1[c], sc = s1[c], sh = s1[64 + c];

  const int R = tid >> 4;
  const int C = tid & 15;
  float acc[4][4];
#pragma unroll
  for (int i = 0; i < 4; ++i)
#pragma unroll
    for (int j = 0; j < 4; ++j) acc[i][j] = 0.0f;
  float szpart = 0.0f;

  const size_t sbase = (size_t)blockIdx.x * 1024;
  for (int t = 0; t < 8; ++t) {
    size_t s0 = sbase + (size_t)t * 128;
#pragma unroll 4
    for (int k = 0; k < 32; ++k) {
      int sl = srow + k * 4;
      float4 g = G[s0 + sl];
      float y = fmaf(w1z, g.z, fmaf(w1y, g.y, fmaf(w1x, g.x, bb)));
      float z = fmaxf(fmaf(sc, y, sh), 0.0f);
      zt[sl][c] = z;
      szpart += z;
    }
    __syncthreads();
#pragma unroll 4
    for (int s = 0; s < 128; ++s) {
      float4 va = *(const float4*)&zt[s][R * 4];
      float4 vb = *(const float4*)&zt[s][C * 4];
      acc[0][0] = fmaf(va.x, vb.x, acc[0][0]); acc[0][1] = fmaf(va.x, vb.y, acc[0][1]);
      acc[0][2] = fmaf(va.x, vb.z, acc[0][2]); acc[0][3] = fmaf(va.x, vb.w, acc[0][3]);
      acc[1][0] = fmaf(va.y, vb.x, acc[1][0]); acc[1][1] = fmaf(va.y, vb.y, acc[1][1]);
      acc[1][2] = fmaf(va.y, vb.z, acc[1][2]); acc[1][3] = fmaf(va.y, vb.w, acc[1][3]);
      acc[2][0] = fmaf(va.z, vb.x, acc[2][0]); acc[2][1] = fmaf(va.z, vb.y, acc[2][1]);
      acc[2][2] = fmaf(va.z, vb.z, acc[2][2]); acc[2][3] = fmaf(va.z, vb.w, acc[2][3]);
      acc[3][0] = fmaf(va.w, vb.x, acc[3][0]); acc[3][1] = fmaf(va.w, vb.y, acc[3][1]);
      acc[3][2] = fmaf(va.w, vb.z, acc[3][2]); acc[3][3] = fmaf(va.w, vb.w, acc[3][3]);
    }
    __syncthreads();
  }

  szred[srow][c] = szpart;
  float* out = zzp + (size_t)blockIdx.x * ZZW;
#pragma unroll
  for (int i = 0; i < 4; ++i)
#pragma unroll
    for (int j = 0; j < 4; ++j)
      out[(R * 4 + i) * 64 + (C * 4 + j)] = acc[i][j];
  __syncthreads();
  if (tid < 64)
    out[4096 + tid] = szred[0][tid] + szred[1][tid] + szred[2][tid] + szred[3][tid];
}

// ---------------------------------------------------------------------------
// K4: reduce zz partials over blocks -> double
// ---------------------------------------------------------------------------
__global__ void zzred_kernel(const float* __restrict__ zzp, double* __restrict__ zzs)
{
  int j = blockIdx.x * 256 + threadIdx.x;
  if (j < ZZW) {
    double s = 0;
    for (int b = 0; b < NBLK_ZZ; ++b) s += (double)zzp[(size_t)b * ZZW + j];
    zzs[j] = s;
  }
}

// ---------------------------------------------------------------------------
// K5: stats2 — BN2 stats via quadratic form (128 blocks = one per channel, 64 thr)
// ---------------------------------------------------------------------------
__global__ void stats2_kernel(const double* __restrict__ zzs,
                              const float* __restrict__ W2, const float* __restrict__ b2,
                              const float* __restrict__ g2, const float* __restrict__ be2,
                              float* __restrict__ s2out)
{
  int d = blockIdx.x;
  int c = threadIdx.x;  // 0..63
  double w_c = (double)W2[(size_t)d * 64 + c];
  double h = 0;
  for (int c2 = 0; c2 < 64; ++c2)
    h += (double)W2[(size_t)d * 64 + c2] * zzs[c * 64 + c2];
  double quad = w_c * h;
  double dz = w_c * zzs[4096 + c];
#pragma unroll
  for (int o = 32; o >= 1; o >>= 1) {
    quad += __shfl_down(quad, o, 64);
    dz += __shfl_down(dz, o, 64);
  }
  if (c == 0) {
    double S = (double)SAMP, b = (double)b2[d];
    double mean = dz / S + b;
    double Ey2 = (quad + 2.0 * b * dz) / S + b * b;
    double var = Ey2 - mean * mean;
    double sc = (double)g2[d] / sqrt(var + 1e-5);
    s2out[d] = (float)sc;
    s2out[128 + d] = (float)((double)be2[d] - mean * sc);
  }
}

// ---------------------------------------------------------------------------
// K6: output pass — register-tiled fp32 GEMM. Block = 256 threads owns
// TM=64 samples x 128 channels. Stage zT[64ch][64s] (transposed) + W2T in
// LDS once (one barrier), then each thread computes an 8-sample x 4-channel
// register tile: per k-step 3x ds_read_b128 feeds 32 fmas (VALU-bound by
// construction; fma floor ~55us). 52 KB LDS -> 3 blocks/CU = 12 waves/CU.
// 8192 blocks.
// ---------------------------------------------------------------------------
__global__ __launch_bounds__(256) void out_kernel(const float4* __restrict__ G,
                                                  const float* __restrict__ W1,
                                                  const float* __restrict__ b1,
                                                  const float* __restrict__ s1,
                                                  const float* __restrict__ W2,
                                                  const float* __restrict__ b2,
                                                  const float* __restrict__ s2,
                                                  float* __restrict__ out)
{
  __shared__ float zT[64][72];     // [channel][sample], row 288B (16B-aligned)
  __shared__ float w2t[64][132];   // [c][d], row 528B (16B-aligned)

  const int tid = threadIdx.x;
  const size_t sbase = (size_t)blockIdx.x * 64;

  // stage W2 transposed: w2t[c][d] = W2[d*64+c]
#pragma unroll
  for (int j = 0; j < 32; ++j) {
    int idx = tid + j * 256;               // 0..8191
    w2t[idx & 63][idx >> 6] = W2[idx];
  }
  // stage zT: thread (zc, zs4) computes z for channel zc, samples zs4+4k
  {
    const int zc = tid & 63, zs4 = tid >> 6;
    const float w1x = W1[zc * 3 + 0], w1y = W1[zc * 3 + 1], w1z = W1[zc * 3 + 2];
    const float bb1 = b1[zc], sc1 = s1[zc], sh1 = s1[64 + zc];
#pragma unroll
    for (int k = 0; k < 16; ++k) {
      int s = zs4 + k * 4;
      float4 g = G[sbase + s];
      float y = fmaf(w1z, g.z, fmaf(w1y, g.y, fmaf(w1x, g.x, bb1)));
      zT[zc][s] = fmaxf(fmaf(sc1, y, sh1), 0.0f);
    }
  }
  __syncthreads();

  const int ds = tid & 31;     // channel group: d = ds*4 .. ds*4+3
  const int sg = tid >> 5;     // sample group: s = sg*8 .. sg*8+7

  float acc[8][4];
#pragma unroll
  for (int i = 0; i < 8; ++i)
#pragma unroll
    for (int j = 0; j < 4; ++j) acc[i][j] = 0.0f;

#pragma unroll 8
  for (int c = 0; c < 64; ++c) {
    const float4* zr4 = (const float4*)&zT[c][0];
    float4 za = zr4[sg * 2];
    float4 zb = zr4[sg * 2 + 1];
    float4 wv = ((const float4*)&w2t[c][0])[ds];
    acc[0][0] = fmaf(za.x, wv.x, acc[0][0]); acc[0][1] = fmaf(za.x, wv.y, acc[0][1]);
    acc[0][2] = fmaf(za.x, wv.z, acc[0][2]); acc[0][3] = fmaf(za.x, wv.w, acc[0][3]);
    acc[1][0] = fmaf(za.y, wv.x, acc[1][0]); acc[1][1] = fmaf(za.y, wv.y, acc[1][1]);
    acc[1][2] = fmaf(za.y, wv.z, acc[1][2]); acc[1][3] = fmaf(za.y, wv.w, acc[1][3]);
    acc[2][0] = fmaf(za.z, wv.x, acc[2][0]); acc[2][1] = fmaf(za.z, wv.y, acc[2][1]);
    acc[2][2] = fmaf(za.z, wv.z, acc[2][2]); acc[2][3] = fmaf(za.z, wv.w, acc[2][3]);
    acc[3][0] = fmaf(za.w, wv.x, acc[3][0]); acc[3][1] = fmaf(za.w, wv.y, acc[3][1]);
    acc[3][2] = fmaf(za.w, wv.z, acc[3][2]); acc[3][3] = fmaf(za.w, wv.w, acc[3][3]);
    acc[4][0] = fmaf(zb.x, wv.x, acc[4][0]); acc[4][1] = fmaf(zb.x, wv.y, acc[4][1]);
    acc[4][2] = fmaf(zb.x, wv.z, acc[4][2]); acc[4][3] = fmaf(zb.x, wv.w, acc[4][3]);
    acc[5][0] = fmaf(zb.y, wv.x, acc[5][0]); acc[5][1] = fmaf(zb.y, wv.y, acc[5][1]);
    acc[5][2] = fmaf(zb.y, wv.z, acc[5][2]); acc[5][3] = fmaf(zb.y, wv.w, acc[5][3]);
    acc[6][0] = fmaf(zb.z, wv.x, acc[6][0]); acc[6][1] = fmaf(zb.z, wv.y, acc[6][1]);
    acc[6][2] = fmaf(zb.z, wv.z, acc[6][2]); acc[6][3] = fmaf(zb.z, wv.w, acc[6][3]);
    acc[7][0] = fmaf(zb.w, wv.x, acc[7][0]); acc[7][1] = fmaf(zb.w, wv.y, acc[7][1]);
    acc[7][2] = fmaf(zb.w, wv.z, acc[7][2]); acc[7][3] = fmaf(zb.w, wv.w, acc[7][3]);
  }

  // epilogue: + b2, BN2 scale/shift, ReLU, float4 stores
  const float4 bv  = *(const float4*)&b2[ds * 4];
  const float4 scv = *(const float4*)&s2[ds * 4];
  const float4 shv = *(const float4*)&s2[128 + ds * 4];
#pragma unroll
  for (int i = 0; i < 8; ++i) {
    float4 o;
    o.x = fmaxf(fmaf(scv.x, acc[i][0] + bv.x, shv.x), 0.0f);
    o.y = fmaxf(fmaf(scv.y, acc[i][1] + bv.y, shv.y), 0.0f);
    o.z = fmaxf(fmaf(scv.z, acc[i][2] + bv.z, shv.z), 0.0f);
    o.w = fmaxf(fmaf(scv.w, acc[i][3] + bv.w, shv.w), 0.0f);
    *(float4*)&out[(sbase + sg * 8 + i) * 128 + ds * 4] = o;
  }
}

// ---------------------------------------------------------------------------
extern "C" void kernel_launch(void* const* d_in, const int* in_sizes, int n_in,
                              void* d_out, int out_size, void* d_ws, size_t ws_size,
                              hipStream_t stream)
{
  const float* points  = (const float*)d_in[0];
  const float* queries = (const float*)d_in[1];
  const float* W1      = (const float*)d_in[2];
  const float* b1      = (const float*)d_in[3];
  const float* gamma1  = (const float*)d_in[4];
  const float* beta1   = (const float*)d_in[5];
  const float* W2      = (const float*)d_in[6];
  const float* b2      = (const float*)d_in[7];
  const float* gamma2  = (const float*)d_in[8];
  const float* beta2   = (const float*)d_in[9];

  char* ws = (char*)d_ws;
  float4* G    = (float4*)(ws + OFF_G);
  float*  gmom = (float*)(ws + OFF_GMOM);
  float*  s1   = (float*)(ws + OFF_S1);
  float*  zzp  = (float*)(ws + OFF_ZZP);
  double* zzs  = (double*)(ws + OFF_ZZS);
  float*  s2   = (float*)(ws + OFF_S2);
  float*  out  = (float*)d_out;

  knn_kernel<<<512, 1024, 0, stream>>>(points, queries, G);
  gmom_kernel<<<256, 256, 0, stream>>>(G, gmom);
  stats1_kernel<<<1, 64, 0, stream>>>(gmom, W1, b1, gamma1, beta1, s1);
  zmom_kernel<<<NBLK_ZZ, 256, 0, stream>>>(G, W1, b1, s1, zzp);
  zzred_kernel<<<17, 256, 0, stream>>>(zzp, zzs);
  stats2_kernel<<<128, 64, 0, stream>>>(zzs, W2, b2, gamma2, beta2, s2);
  out_kernel<<<8192, 256, 0, stream>>>(G, W1, b1, s1, W2, b2, s2, out);
}

// Round 5
// 334.850 us; speedup vs baseline: 3.2664x; 1.0828x over previous
//
#include <hip/hip_runtime.h>
#include <cmath>

// Problem constants
constexpr int BB = 4, LL = 8, NPTS = 4096, MQ = 1024, KNNK = 16;
constexpr int C1 = 64, C2 = 128;
constexpr int NSLICE = BB * LL;                       // 32
constexpr long long SAMP = (long long)NSLICE * MQ * KNNK;  // 524288 samples
constexpr int NBLK_ZZ = 512;
constexpr int ZZW = C1 * C1 + C1;                     // 4160 (full 64x64 + sum_z)

// Workspace layout (bytes)
constexpr size_t OFF_G    = 0;                                   // float4[SAMP] = 8 MB
constexpr size_t OFF_GMOM = (size_t)8 * 1024 * 1024;             // float[256*9]
constexpr size_t OFF_S1   = OFF_GMOM + 16384;                    // float[128]: scale1,shift1
constexpr size_t OFF_ZZP  = OFF_S1 + 1024;                       // float[NBLK_ZZ*ZZW]
constexpr size_t OFF_ZZS  = OFF_ZZP + (size_t)NBLK_ZZ * ZZW * 4; // double[ZZW]
constexpr size_t OFF_S2   = OFF_ZZS + (size_t)ZZW * 8;           // float[256]: scale2,shift2

// ---------------------------------------------------------------------------
// K1: per-slice KNN + gather. One wave serves FOUR queries (4 segments of 16
// lanes, distributed sorted lists). Iteration 0 is seeded by a 64-lane
// bitonic sort (keys = monotone-mapped d || lane, 4 queries in lockstep) —
// replaces the 64-round "flood" of inserts with ~1.7K cycles and produces a
// result bit-identical to index-order strict-< insertion (lex (d,idx) order
// == jax.lax.top_k stable tie handling). Iterations 1..63 use ballot + pop
// rounds as before. d2 arithmetic replicates the reference exactly.
// Grid: 512 blocks x 1024 threads; 64KB LDS -> 2 blocks/CU -> 32 waves/CU.
// ---------------------------------------------------------------------------
__global__ __launch_bounds__(1024, 8) void knn_kernel(const float* __restrict__ pts,
                                                      const float* __restrict__ qrs,
                                                      float4* __restrict__ G)
{
#pragma clang fp contract(off)
  __shared__ float4 sp[NPTS];   // (x,y,z,p2) = 64 KB
  const int tid = threadIdx.x;
  const int bl = blockIdx.x >> 4;    // slice (32)
  const int qt = blockIdx.x & 15;    // 16 query tiles of 64
  const int wave = tid >> 6;
  const int lane = tid & 63;
  const float INF = 3.402823466e38f;

  const float* pb = pts + (size_t)bl * NPTS * 3;
  for (int p = tid; p < NPTS; p += 1024) {
    float x = pb[p * 3 + 0], y = pb[p * 3 + 1], z = pb[p * 3 + 2];
    float pp = (x * x + y * y) + z * z;       // plain rounding
    sp[p] = make_float4(x, y, z, pp);
  }
  __syncthreads();

  const int qbase = qt * 64 + wave * 4;
  const float* qp = qrs + ((size_t)bl * MQ + qbase) * 3;
  const float qxA = qp[0], qyA = qp[1], qzA = qp[2];
  const float qxB = qp[3], qyB = qp[4], qzB = qp[5];
  const float qxC = qp[6], qyC = qp[7], qzC = qp[8];
  const float qxD = qp[9], qyD = qp[10], qzD = qp[11];
  const float q2A = (qxA * qxA + qyA * qyA) + qzA * qzA;   // plain rounding
  const float q2B = (qxB * qxB + qyB * qyB) + qzB * qzB;
  const float q2C = (qxC * qxC + qyC * qyC) + qzC * qzC;
  const float q2D = (qxD * qxD + qyD * qyD) + qzD * qzD;

  const int seg = lane >> 4;
  const bool segHead = (lane & 15) == 0;

  float Ld; int Li;
  float tauA, tauB, tauC, tauD;

  // ---- seed (i = 0): bitonic sort of 64 (d, lane) keys per query ----
  {
    float4 P = sp[lane];
    float pqA = fmaf(P.z, qzA, fmaf(P.y, qyA, P.x * qxA));
    float pqB = fmaf(P.z, qzB, fmaf(P.y, qyB, P.x * qxB));
    float pqC = fmaf(P.z, qzC, fmaf(P.y, qyC, P.x * qxC));
    float pqD = fmaf(P.z, qzD, fmaf(P.y, qyD, P.x * qxD));
    float dA = fmaf(-2.0f, pqA, q2A + P.w);
    float dB = fmaf(-2.0f, pqB, q2B + P.w);
    float dC = fmaf(-2.0f, pqC, q2C + P.w);
    float dD = fmaf(-2.0f, pqD, q2D + P.w);

    // monotone float->uint map (handles possibly-negative computed d2)
    unsigned uA = __float_as_uint(dA); uA = (uA & 0x80000000u) ? ~uA : (uA | 0x80000000u);
    unsigned uB = __float_as_uint(dB); uB = (uB & 0x80000000u) ? ~uB : (uB | 0x80000000u);
    unsigned uC = __float_as_uint(dC); uC = (uC & 0x80000000u) ? ~uC : (uC | 0x80000000u);
    unsigned uD = __float_as_uint(dD); uD = (uD & 0x80000000u) ? ~uD : (uD | 0x80000000u);
    unsigned long long kA = ((unsigned long long)uA << 6) | (unsigned)lane;
    unsigned long long kB = ((unsigned long long)uB << 6) | (unsigned)lane;
    unsigned long long kC = ((unsigned long long)uC << 6) | (unsigned)lane;
    unsigned long long kD = ((unsigned long long)uD << 6) | (unsigned)lane;

#pragma unroll
    for (int k = 2; k <= 64; k <<= 1) {
#pragma unroll
      for (int j = k >> 1; j >= 1; j >>= 1) {
        const bool selMin = ((lane & j) == 0) == ((lane & k) == 0);
        unsigned long long pA = __shfl_xor(kA, j, 64);
        unsigned long long pB = __shfl_xor(kB, j, 64);
        unsigned long long pC = __shfl_xor(kC, j, 64);
        unsigned long long pD = __shfl_xor(kD, j, 64);
        kA = ((kA < pA) == selMin) ? kA : pA;
        kB = ((kB < pB) == selMin) ? kB : pB;
        kC = ((kC < pC) == selMin) ? kC : pC;
        kD = ((kD < pD) == selMin) ? kD : pD;
      }
    }

    // redistribute: lane takes rank (lane&15) of its segment's query
    const int src = lane & 15;
    unsigned long long rA = __shfl(kA, src, 64);
    unsigned long long rB = __shfl(kB, src, 64);
    unsigned long long rC = __shfl(kC, src, 64);
    unsigned long long rD = __shfl(kD, src, 64);
    unsigned long long r0 = (seg & 1) ? rB : rA;
    unsigned long long r1 = (seg & 1) ? rD : rC;
    unsigned long long rr = (seg & 2) ? r1 : r0;
    unsigned um = (unsigned)(rr >> 6);
    um = (um & 0x80000000u) ? (um & 0x7fffffffu) : ~um;    // inverse map
    Ld = __uint_as_float(um);
    Li = (int)(rr & 63u);
    tauA = __shfl(Ld, 15, 64);
    tauB = __shfl(Ld, 31, 64);
    tauC = __shfl(Ld, 47, 64);
    tauD = __shfl(Ld, 63, 64);
  }

  // ---- main scan: i = 1..63 ----
  for (int i = 1; i < 64; ++i) {
    float4 P = sp[i * 64 + lane];
    float pqA = fmaf(P.z, qzA, fmaf(P.y, qyA, P.x * qxA));
    float pqB = fmaf(P.z, qzB, fmaf(P.y, qyB, P.x * qxB));
    float pqC = fmaf(P.z, qzC, fmaf(P.y, qyC, P.x * qxC));
    float pqD = fmaf(P.z, qzD, fmaf(P.y, qyD, P.x * qxD));
    float dA = fmaf(-2.0f, pqA, q2A + P.w);
    float dB = fmaf(-2.0f, pqB, q2B + P.w);
    float dC = fmaf(-2.0f, pqC, q2C + P.w);
    float dD = fmaf(-2.0f, pqD, q2D + P.w);

    unsigned long long mA = __ballot(dA < tauA);
    unsigned long long mB = __ballot(dB < tauB);
    unsigned long long mC = __ballot(dC < tauC);
    unsigned long long mD = __ballot(dD < tauD);

    if (mA | mB | mC | mD) {
      do {
        float vA = INF, vB = INF, vC = INF, vD = INF;
        int iA = 0, iB = 0, iC = 0, iD = 0;
        if (mA) { int b = (int)__builtin_ctzll(mA); mA &= mA - 1;
                  vA = __shfl(dA, b, 64); iA = i * 64 + b; }
        if (mB) { int b = (int)__builtin_ctzll(mB); mB &= mB - 1;
                  vB = __shfl(dB, b, 64); iB = i * 64 + b; }
        if (mC) { int b = (int)__builtin_ctzll(mC); mC &= mC - 1;
                  vC = __shfl(dC, b, 64); iC = i * 64 + b; }
        if (mD) { int b = (int)__builtin_ctzll(mD); mD &= mD - 1;
                  vD = __shfl(dD, b, 64); iD = i * 64 + b; }
        float v0 = (seg & 1) ? vB : vA;
        float v1 = (seg & 1) ? vD : vC;
        float v  = (seg & 2) ? v1 : v0;
        int  i0 = (seg & 1) ? iB : iA;
        int  i1 = (seg & 1) ? iD : iC;
        int  vi = (seg & 2) ? i1 : i0;
        float pd = __shfl_up(Ld, 1, 64);
        int   pi = __shfl_up(Li, 1, 64);
        if (segHead) pd = -INF;
        bool gt  = Ld > v;     // strict: equals keep rank (lower idx first)
        bool gtp = pd > v;
        Ld = gt ? (gtp ? pd : v) : Ld;
        Li = gt ? (gtp ? pi : vi) : Li;
      } while (mA | mB | mC | mD);
      tauA = __shfl(Ld, 15, 64);
      tauB = __shfl(Ld, 31, 64);
      tauC = __shfl(Ld, 47, 64);
      tauD = __shfl(Ld, 63, 64);
    }
  }

  float4 P = sp[Li];
  G[((size_t)bl * MQ + qbase + seg) * KNNK + (lane & 15)] =
      make_float4(P.x, P.y, P.z, 0.0f);
}

// ---------------------------------------------------------------------------
// K1b: coordinate moments from G (256 blocks x 256 threads, 8 samples/thread)
// ---------------------------------------------------------------------------
__global__ __launch_bounds__(256) void gmom_kernel(const float4* __restrict__ G,
                                                   float* __restrict__ gmom)
{
  __shared__ float sr[256 * 9];
  const int tid = threadIdx.x;
  float s[9];
#pragma unroll
  for (int j = 0; j < 9; ++j) s[j] = 0.0f;
  size_t base = (size_t)blockIdx.x * 2048 + tid;
#pragma unroll
  for (int k = 0; k < 8; ++k) {
    float4 P = G[base + (size_t)k * 256];
    s[0] += P.x; s[1] += P.y; s[2] += P.z;
    s[3] = fmaf(P.x, P.x, s[3]); s[4] = fmaf(P.y, P.y, s[4]); s[5] = fmaf(P.z, P.z, s[5]);
    s[6] = fmaf(P.x, P.y, s[6]); s[7] = fmaf(P.x, P.z, s[7]); s[8] = fmaf(P.y, P.z, s[8]);
  }
#pragma unroll
  for (int j = 0; j < 9; ++j) sr[tid * 9 + j] = s[j];
  __syncthreads();
  if (tid < 9) {
    float acc = 0;
    for (int r = 0; r < 256; ++r) acc += sr[r * 9 + tid];
    gmom[blockIdx.x * 9 + tid] = acc;
  }
}

// ---------------------------------------------------------------------------
// K2: stats1 — analytic BN1 stats from coord moments (1 block, 64 threads)
// ---------------------------------------------------------------------------
__global__ void stats1_kernel(const float* __restrict__ gmom,
                              const float* __restrict__ W1, const float* __restrict__ b1,
                              const float* __restrict__ g1, const float* __restrict__ be1,
                              float* __restrict__ s1out)
{
  __shared__ double m[9];
  if (threadIdx.x < 9) {
    double s = 0;
    for (int r = 0; r < 256; ++r) s += (double)gmom[r * 9 + threadIdx.x];
    m[threadIdx.x] = s / (double)SAMP;
  }
  __syncthreads();
  int c = threadIdx.x;  // 0..63
  double Ex = m[0], Ey = m[1], Ez = m[2];
  double Exx = m[3], Eyy = m[4], Ezz = m[5], Exy = m[6], Exz = m[7], Eyz = m[8];
  double wx = W1[c * 3 + 0], wy = W1[c * 3 + 1], wz = W1[c * 3 + 2], b = b1[c];
  double dot = wx * Ex + wy * Ey + wz * Ez;
  double mean = dot + b;
  double Ey2 = wx * wx * Exx + wy * wy * Eyy + wz * wz * Ezz
             + 2.0 * (wx * wy * Exy + wx * wz * Exz + wy * wz * Eyz)
             + 2.0 * b * dot + b * b;
  double var = Ey2 - mean * mean;
  double sc = (double)g1[c] / sqrt(var + 1e-5);
  s1out[c] = (float)sc;
  s1out[64 + c] = (float)((double)be1[c] - mean * sc);
}

// ---------------------------------------------------------------------------
// K3: z moments — recompute z1 from G, accumulate sum_z (64) and sum z z^T (64x64)
// ---------------------------------------------------------------------------
__global__ __launch_bounds__(256) void zmom_kernel(const float4* __restrict__ G,
                                                   const float* __restrict__ W1,
                                                   const float* __restrict__ b1,
                                                   const float* __restrict__ s1,
                                                   float* __restrict__ zzp)
{
  __shared__ float zt[128][68];     // rows 16B-aligned
  __shared__ float szred[4][64];

  const int tid = threadIdx.x;
  const int c = tid & 63;
  const int srow = tid >> 6;
  const float w1x = W1[c * 3 + 0], w1y = W1[c * 3 + 1], w1z = W1[c * 3 + 2];
  const float bb = b1[c], sc = s1[c], sh = s1[64 + c];

  const int R = tid >> 4;
  const int C = tid & 15;
  float acc[4][4];
#pragma unroll
  for (int i = 0; i < 4; ++i)
#pragma unroll
    for (int j = 0; j < 4; ++j) acc[i][j] = 0.0f;
  float szpart = 0.0f;

  const size_t sbase = (size_t)blockIdx.x * 1024;
  for (int t = 0; t < 8; ++t) {
    size_t s0 = sbase + (size_t)t * 128;
#pragma unroll 4
    for (int k = 0; k < 32; ++k) {
      int sl = srow + k * 4;
      float4 g = G[s0 + sl];
      float y = fmaf(w1z, g.z, fmaf(w1y, g.y, fmaf(w1x, g.x, bb)));
      float z = fmaxf(fmaf(sc, y, sh), 0.0f);
      zt[sl][c] = z;
      szpart += z;
    }
    __syncthreads();
#pragma unroll 4
    for (int s = 0; s < 128; ++s) {
      float4 va = *(const float4*)&zt[s][R * 4];
      float4 vb = *(const float4*)&zt[s][C * 4];
      acc[0][0] = fmaf(va.x, vb.x, acc[0][0]); acc[0][1] = fmaf(va.x, vb.y, acc[0][1]);
      acc[0][2] = fmaf(va.x, vb.z, acc[0][2]); acc[0][3] = fmaf(va.x, vb.w, acc[0][3]);
      acc[1][0] = fmaf(va.y, vb.x, acc[1][0]); acc[1][1] = fmaf(va.y, vb.y, acc[1][1]);
      acc[1][2] = fmaf(va.y, vb.z, acc[1][2]); acc[1][3] = fmaf(va.y, vb.w, acc[1][3]);
      acc[2][0] = fmaf(va.z, vb.x, acc[2][0]); acc[2][1] = fmaf(va.z, vb.y, acc[2][1]);
      acc[2][2] = fmaf(va.z, vb.z, acc[2][2]); acc[2][3] = fmaf(va.z, vb.w, acc[2][3]);
      acc[3][0] = fmaf(va.w, vb.x, acc[3][0]); acc[3][1] = fmaf(va.w, vb.y, acc[3][1]);
      acc[3][2] = fmaf(va.w, vb.z, acc[3][2]); acc[3][3] = fmaf(va.w, vb.w, acc[3][3]);
    }
    __syncthreads();
  }

  szred[srow][c] = szpart;
  float* out = zzp + (size_t)blockIdx.x * ZZW;
#pragma unroll
  for (int i = 0; i < 4; ++i)
#pragma unroll
    for (int j = 0; j < 4; ++j)
      out[(R * 4 + i) * 64 + (C * 4 + j)] = acc[i][j];
  __syncthreads();
  if (tid < 64)
    out[4096 + tid] = szred[0][tid] + szred[1][tid] + szred[2][tid] + szred[3][tid];
}

// ---------------------------------------------------------------------------
// K4: reduce zz partials over blocks -> double
// ---------------------------------------------------------------------------
__global__ void zzred_kernel(const float* __restrict__ zzp, double* __restrict__ zzs)
{
  int j = blockIdx.x * 256 + threadIdx.x;
  if (j < ZZW) {
    double s = 0;
    for (int b = 0; b < NBLK_ZZ; ++b) s += (double)zzp[(size_t)b * ZZW + j];
    zzs[j] = s;
  }
}

// ---------------------------------------------------------------------------
// K5: stats2 — BN2 stats via quadratic form (128 blocks = one per channel, 64 thr)
// ---------------------------------------------------------------------------
__global__ void stats2_kernel(const double* __restrict__ zzs,
                              const float* __restrict__ W2, const float* __restrict__ b2,
                              const float* __restrict__ g2, const float* __restrict__ be2,
                              float* __restrict__ s2out)
{
  int d = blockIdx.x;
  int c = threadIdx.x;  // 0..63
  double w_c = (double)W2[(size_t)d * 64 + c];
  double h = 0;
  for (int c2 = 0; c2 < 64; ++c2)
    h += (double)W2[(size_t)d * 64 + c2] * zzs[c * 64 + c2];
  double quad = w_c * h;
  double dz = w_c * zzs[4096 + c];
#pragma unroll
  for (int o = 32; o >= 1; o >>= 1) {
    quad += __shfl_down(quad, o, 64);
    dz += __shfl_down(dz, o, 64);
  }
  if (c == 0) {
    double S = (double)SAMP, b = (double)b2[d];
    double mean = dz / S + b;
    double Ey2 = (quad + 2.0 * b * dz) / S + b * b;
    double var = Ey2 - mean * mean;
    double sc = (double)g2[d] / sqrt(var + 1e-5);
    s2out[d] = (float)sc;
    s2out[128 + d] = (float)((double)be2[d] - mean * sc);
  }
}

// ---------------------------------------------------------------------------
// K6: output pass — register-tiled fp32 GEMM (see R4 notes). 8192 blocks.
// ---------------------------------------------------------------------------
__global__ __launch_bounds__(256) void out_kernel(const float4* __restrict__ G,
                                                  const float* __restrict__ W1,
                                                  const float* __restrict__ b1,
                                                  const float* __restrict__ s1,
                                                  const float* __restrict__ W2,
                                                  const float* __restrict__ b2,
                                                  const float* __restrict__ s2,
                                                  float* __restrict__ out)
{
  __shared__ float zT[64][72];     // [channel][sample]
  __shared__ float w2t[64][132];   // [c][d]

  const int tid = threadIdx.x;
  const size_t sbase = (size_t)blockIdx.x * 64;

#pragma unroll
  for (int j = 0; j < 32; ++j) {
    int idx = tid + j * 256;               // 0..8191
    w2t[idx & 63][idx >> 6] = W2[idx];
  }
  {
    const int zc = tid & 63, zs4 = tid >> 6;
    const float w1x = W1[zc * 3 + 0], w1y = W1[zc * 3 + 1], w1z = W1[zc * 3 + 2];
    const float bb1 = b1[zc], sc1 = s1[zc], sh1 = s1[64 + zc];
#pragma unroll
    for (int k = 0; k < 16; ++k) {
      int s = zs4 + k * 4;
      float4 g = G[sbase + s];
      float y = fmaf(w1z, g.z, fmaf(w1y, g.y, fmaf(w1x, g.x, bb1)));
      zT[zc][s] = fmaxf(fmaf(sc1, y, sh1), 0.0f);
    }
  }
  __syncthreads();

  const int ds = tid & 31;     // channel group: d = ds*4 .. ds*4+3
  const int sg = tid >> 5;     // sample group: s = sg*8 .. sg*8+7

  float acc[8][4];
#pragma unroll
  for (int i = 0; i < 8; ++i)
#pragma unroll
    for (int j = 0; j < 4; ++j) acc[i][j] = 0.0f;

#pragma unroll 8
  for (int c = 0; c < 64; ++c) {
    const float4* zr4 = (const float4*)&zT[c][0];
    float4 za = zr4[sg * 2];
    float4 zb = zr4[sg * 2 + 1];
    float4 wv = ((const float4*)&w2t[c][0])[ds];
    acc[0][0] = fmaf(za.x, wv.x, acc[0][0]); acc[0][1] = fmaf(za.x, wv.y, acc[0][1]);
    acc[0][2] = fmaf(za.x, wv.z, acc[0][2]); acc[0][3] = fmaf(za.x, wv.w, acc[0][3]);
    acc[1][0] = fmaf(za.y, wv.x, acc[1][0]); acc[1][1] = fmaf(za.y, wv.y, acc[1][1]);
    acc[1][2] = fmaf(za.y, wv.z, acc[1][2]); acc[1][3] = fmaf(za.y, wv.w, acc[1][3]);
    acc[2][0] = fmaf(za.z, wv.x, acc[2][0]); acc[2][1] = fmaf(za.z, wv.y, acc[2][1]);
    acc[2][2] = fmaf(za.z, wv.z, acc[2][2]); acc[2][3] = fmaf(za.z, wv.w, acc[2][3]);
    acc[3][0] = fmaf(za.w, wv.x, acc[3][0]); acc[3][1] = fmaf(za.w, wv.y, acc[3][1]);
    acc[3][2] = fmaf(za.w, wv.z, acc[3][2]); acc[3][3] = fmaf(za.w, wv.w, acc[3][3]);
    acc[4][0] = fmaf(zb.x, wv.x, acc[4][0]); acc[4][1] = fmaf(zb.x, wv.y, acc[4][1]);
    acc[4][2] = fmaf(zb.x, wv.z, acc[4][2]); acc[4][3] = fmaf(zb.x, wv.w, acc[4][3]);
    acc[5][0] = fmaf(zb.y, wv.x, acc[5][0]); acc[5][1] = fmaf(zb.y, wv.y, acc[5][1]);
    acc[5][2] = fmaf(zb.y, wv.z, acc[5][2]); acc[5][3] = fmaf(zb.y, wv.w, acc[5][3]);
    acc[6][0] = fmaf(zb.z, wv.x, acc[6][0]); acc[6][1] = fmaf(zb.z, wv.y, acc[6][1]);
    acc[6][2] = fmaf(zb.z, wv.z, acc[6][2]); acc[6][3] = fmaf(zb.z, wv.w, acc[6][3]);
    acc[7][0] = fmaf(zb.w, wv.x, acc[7][0]); acc[7][1] = fmaf(zb.w, wv.y, acc[7][1]);
    acc[7][2] = fmaf(zb.w, wv.z, acc[7][2]); acc[7][3] = fmaf(zb.w, wv.w, acc[7][3]);
  }

  const float4 bv  = *(const float4*)&b2[ds * 4];
  const float4 scv = *(const float4*)&s2[ds * 4];
  const float4 shv = *(const float4*)&s2[128 + ds * 4];
#pragma unroll
  for (int i = 0; i < 8; ++i) {
    float4 o;
    o.x = fmaxf(fmaf(scv.x, acc[i][0] + bv.x, shv.x), 0.0f);
    o.y = fmaxf(fmaf(scv.y, acc[i][1] + bv.y, shv.y), 0.0f);
    o.z = fmaxf(fmaf(scv.z, acc[i][2] + bv.z, shv.z), 0.0f);
    o.w = fmaxf(fmaf(scv.w, acc[i][3] + bv.w, shv.w), 0.0f);
    *(float4*)&out[(sbase + sg * 8 + i) * 128 + ds * 4] = o;
  }
}

// ---------------------------------------------------------------------------
extern "C" void kernel_launch(void* const* d_in, const int* in_sizes, int n_in,
                              void* d_out, int out_size, void* d_ws, size_t ws_size,
                              hipStream_t stream)
{
  const float* points  = (const float*)d_in[0];
  const float* queries = (const float*)d_in[1];
  const float* W1      = (const float*)d_in[2];
  const float* b1      = (const float*)d_in[3];
  const float* gamma1  = (const float*)d_in[4];
  const float* beta1   = (const float*)d_in[5];
  const float* W2      = (const float*)d_in[6];
  const float* b2      = (const float*)d_in[7];
  const float* gamma2  = (const float*)d_in[8];
  const float* beta2   = (const float*)d_in[9];

  char* ws = (char*)d_ws;
  float4* G    = (float4*)(ws + OFF_G);
  float*  gmom = (float*)(ws + OFF_GMOM);
  float*  s1   = (float*)(ws + OFF_S1);
  float*  zzp  = (float*)(ws + OFF_ZZP);
  double* zzs  = (double*)(ws + OFF_ZZS);
  float*  s2   = (float*)(ws + OFF_S2);
  float*  out  = (float*)d_out;

  knn_kernel<<<512, 1024, 0, stream>>>(points, queries, G);
  gmom_kernel<<<256, 256, 0, stream>>>(G, gmom);
  stats1_kernel<<<1, 64, 0, stream>>>(gmom, W1, b1, gamma1, beta1, s1);
  zmom_kernel<<<NBLK_ZZ, 256, 0, stream>>>(G, W1, b1, s1, zzp);
  zzred_kernel<<<17, 256, 0, stream>>>(zzp, zzs);
  stats2_kernel<<<128, 64, 0, stream>>>(zzs, W2, b2, gamma2, beta2, s2);
  out_kernel<<<8192, 256, 0, stream>>>(G, W1, b1, s1, W2, b2, s2, out);
}

// Round 6
// 283.844 us; speedup vs baseline: 3.8533x; 1.1797x over previous
//
#include <hip/hip_runtime.h>
#include <cmath>

// Problem constants
constexpr int BB = 4, LL = 8, NPTS = 4096, MQ = 1024, KNNK = 16;
constexpr int C1 = 64, C2 = 128;
constexpr int NSLICE = BB * LL;                       // 32
constexpr long long SAMP = (long long)NSLICE * MQ * KNNK;  // 524288 samples
constexpr int NBLK_ZZ = 512;
constexpr int ZZW = C1 * C1 + C1;                     // 4160 (full 64x64 + sum_z)

// Workspace layout (bytes)
constexpr size_t OFF_G    = 0;                                   // float4[SAMP] = 8 MB
constexpr size_t OFF_GMOM = (size_t)8 * 1024 * 1024;             // float[256*9]
constexpr size_t OFF_S1   = OFF_GMOM + 16384;                    // float[128]: scale1,shift1
constexpr size_t OFF_ZZP  = OFF_S1 + 1024;                       // float[NBLK_ZZ*ZZW]
constexpr size_t OFF_ZZS  = OFF_ZZP + (size_t)NBLK_ZZ * ZZW * 4; // double[ZZW]
constexpr size_t OFF_S2   = OFF_ZZS + (size_t)ZZW * 8;           // float[256]: scale2,shift2
// W2 hi/lo bf16 splits: reuse the zzp region (dead after zzred, before stats2)
constexpr size_t OFF_W2H  = OFF_ZZP;                             // ushort[8192] = 16KB
constexpr size_t OFF_W2L  = OFF_ZZP + 16384;                     // ushort[8192] = 16KB

typedef __attribute__((ext_vector_type(8))) short short8_b;   // 8 bf16 (4 VGPRs)
typedef __attribute__((ext_vector_type(4))) float f32x4;

__device__ inline ushort f2bf(float f) {        // RNE float -> bf16 bits
  unsigned u = __float_as_uint(f);
  return (ushort)((u + 0x7fffu + ((u >> 16) & 1u)) >> 16);
}

// ---------------------------------------------------------------------------
// K1: per-slice KNN + gather (bitonic seed + segmented ballot inserts).
// See R2-R5 notes. 512 blocks x 1024 threads.
// ---------------------------------------------------------------------------
__global__ __launch_bounds__(1024, 8) void knn_kernel(const float* __restrict__ pts,
                                                      const float* __restrict__ qrs,
                                                      float4* __restrict__ G)
{
#pragma clang fp contract(off)
  __shared__ float4 sp[NPTS];   // (x,y,z,p2) = 64 KB
  const int tid = threadIdx.x;
  const int bl = blockIdx.x >> 4;    // slice (32)
  const int qt = blockIdx.x & 15;    // 16 query tiles of 64
  const int wave = tid >> 6;
  const int lane = tid & 63;
  const float INF = 3.402823466e38f;

  const float* pb = pts + (size_t)bl * NPTS * 3;
  for (int p = tid; p < NPTS; p += 1024) {
    float x = pb[p * 3 + 0], y = pb[p * 3 + 1], z = pb[p * 3 + 2];
    float pp = (x * x + y * y) + z * z;       // plain rounding
    sp[p] = make_float4(x, y, z, pp);
  }
  __syncthreads();

  const int qbase = qt * 64 + wave * 4;
  const float* qp = qrs + ((size_t)bl * MQ + qbase) * 3;
  const float qxA = qp[0], qyA = qp[1], qzA = qp[2];
  const float qxB = qp[3], qyB = qp[4], qzB = qp[5];
  const float qxC = qp[6], qyC = qp[7], qzC = qp[8];
  const float qxD = qp[9], qyD = qp[10], qzD = qp[11];
  const float q2A = (qxA * qxA + qyA * qyA) + qzA * qzA;   // plain rounding
  const float q2B = (qxB * qxB + qyB * qyB) + qzB * qzB;
  const float q2C = (qxC * qxC + qyC * qyC) + qzC * qzC;
  const float q2D = (qxD * qxD + qyD * qyD) + qzD * qzD;

  const int seg = lane >> 4;
  const bool segHead = (lane & 15) == 0;

  float Ld; int Li;
  float tauA, tauB, tauC, tauD;

  // ---- seed (i = 0): bitonic sort of 64 (d, lane) keys per query ----
  {
    float4 P = sp[lane];
    float pqA = fmaf(P.z, qzA, fmaf(P.y, qyA, P.x * qxA));
    float pqB = fmaf(P.z, qzB, fmaf(P.y, qyB, P.x * qxB));
    float pqC = fmaf(P.z, qzC, fmaf(P.y, qyC, P.x * qxC));
    float pqD = fmaf(P.z, qzD, fmaf(P.y, qyD, P.x * qxD));
    float dA = fmaf(-2.0f, pqA, q2A + P.w);
    float dB = fmaf(-2.0f, pqB, q2B + P.w);
    float dC = fmaf(-2.0f, pqC, q2C + P.w);
    float dD = fmaf(-2.0f, pqD, q2D + P.w);

    unsigned uA = __float_as_uint(dA); uA = (uA & 0x80000000u) ? ~uA : (uA | 0x80000000u);
    unsigned uB = __float_as_uint(dB); uB = (uB & 0x80000000u) ? ~uB : (uB | 0x80000000u);
    unsigned uC = __float_as_uint(dC); uC = (uC & 0x80000000u) ? ~uC : (uC | 0x80000000u);
    unsigned uD = __float_as_uint(dD); uD = (uD & 0x80000000u) ? ~uD : (uD | 0x80000000u);
    unsigned long long kA = ((unsigned long long)uA << 6) | (unsigned)lane;
    unsigned long long kB = ((unsigned long long)uB << 6) | (unsigned)lane;
    unsigned long long kC = ((unsigned long long)uC << 6) | (unsigned)lane;
    unsigned long long kD = ((unsigned long long)uD << 6) | (unsigned)lane;

#pragma unroll
    for (int k = 2; k <= 64; k <<= 1) {
#pragma unroll
      for (int j = k >> 1; j >= 1; j >>= 1) {
        const bool selMin = ((lane & j) == 0) == ((lane & k) == 0);
        unsigned long long pA = __shfl_xor(kA, j, 64);
        unsigned long long pB = __shfl_xor(kB, j, 64);
        unsigned long long pC = __shfl_xor(kC, j, 64);
        unsigned long long pD = __shfl_xor(kD, j, 64);
        kA = ((kA < pA) == selMin) ? kA : pA;
        kB = ((kB < pB) == selMin) ? kB : pB;
        kC = ((kC < pC) == selMin) ? kC : pC;
        kD = ((kD < pD) == selMin) ? kD : pD;
      }
    }

    const int src = lane & 15;
    unsigned long long rA = __shfl(kA, src, 64);
    unsigned long long rB = __shfl(kB, src, 64);
    unsigned long long rC = __shfl(kC, src, 64);
    unsigned long long rD = __shfl(kD, src, 64);
    unsigned long long r0 = (seg & 1) ? rB : rA;
    unsigned long long r1 = (seg & 1) ? rD : rC;
    unsigned long long rr = (seg & 2) ? r1 : r0;
    unsigned um = (unsigned)(rr >> 6);
    um = (um & 0x80000000u) ? (um & 0x7fffffffu) : ~um;    // inverse map
    Ld = __uint_as_float(um);
    Li = (int)(rr & 63u);
    tauA = __shfl(Ld, 15, 64);
    tauB = __shfl(Ld, 31, 64);
    tauC = __shfl(Ld, 47, 64);
    tauD = __shfl(Ld, 63, 64);
  }

  // ---- main scan: i = 1..63 ----
  for (int i = 1; i < 64; ++i) {
    float4 P = sp[i * 64 + lane];
    float pqA = fmaf(P.z, qzA, fmaf(P.y, qyA, P.x * qxA));
    float pqB = fmaf(P.z, qzB, fmaf(P.y, qyB, P.x * qxB));
    float pqC = fmaf(P.z, qzC, fmaf(P.y, qyC, P.x * qxC));
    float pqD = fmaf(P.z, qzD, fmaf(P.y, qyD, P.x * qxD));
    float dA = fmaf(-2.0f, pqA, q2A + P.w);
    float dB = fmaf(-2.0f, pqB, q2B + P.w);
    float dC = fmaf(-2.0f, pqC, q2C + P.w);
    float dD = fmaf(-2.0f, pqD, q2D + P.w);

    unsigned long long mA = __ballot(dA < tauA);
    unsigned long long mB = __ballot(dB < tauB);
    unsigned long long mC = __ballot(dC < tauC);
    unsigned long long mD = __ballot(dD < tauD);

    if (mA | mB | mC | mD) {
      do {
        float vA = INF, vB = INF, vC = INF, vD = INF;
        int iA = 0, iB = 0, iC = 0, iD = 0;
        if (mA) { int b = (int)__builtin_ctzll(mA); mA &= mA - 1;
                  vA = __shfl(dA, b, 64); iA = i * 64 + b; }
        if (mB) { int b = (int)__builtin_ctzll(mB); mB &= mB - 1;
                  vB = __shfl(dB, b, 64); iB = i * 64 + b; }
        if (mC) { int b = (int)__builtin_ctzll(mC); mC &= mC - 1;
                  vC = __shfl(dC, b, 64); iC = i * 64 + b; }
        if (mD) { int b = (int)__builtin_ctzll(mD); mD &= mD - 1;
                  vD = __shfl(dD, b, 64); iD = i * 64 + b; }
        float v0 = (seg & 1) ? vB : vA;
        float v1 = (seg & 1) ? vD : vC;
        float v  = (seg & 2) ? v1 : v0;
        int  i0 = (seg & 1) ? iB : iA;
        int  i1 = (seg & 1) ? iD : iC;
        int  vi = (seg & 2) ? i1 : i0;
        float pd = __shfl_up(Ld, 1, 64);
        int   pi = __shfl_up(Li, 1, 64);
        if (segHead) pd = -INF;
        bool gt  = Ld > v;     // strict: equals keep rank (lower idx first)
        bool gtp = pd > v;
        Ld = gt ? (gtp ? pd : v) : Ld;
        Li = gt ? (gtp ? pi : vi) : Li;
      } while (mA | mB | mC | mD);
      tauA = __shfl(Ld, 15, 64);
      tauB = __shfl(Ld, 31, 64);
      tauC = __shfl(Ld, 47, 64);
      tauD = __shfl(Ld, 63, 64);
    }
  }

  float4 P = sp[Li];
  G[((size_t)bl * MQ + qbase + seg) * KNNK + (lane & 15)] =
      make_float4(P.x, P.y, P.z, 0.0f);
}

// ---------------------------------------------------------------------------
// K1b: coordinate moments from G (256 blocks x 256 threads, 8 samples/thread)
// ---------------------------------------------------------------------------
__global__ __launch_bounds__(256) void gmom_kernel(const float4* __restrict__ G,
                                                   float* __restrict__ gmom)
{
  __shared__ float sr[256 * 9];
  const int tid = threadIdx.x;
  float s[9];
#pragma unroll
  for (int j = 0; j < 9; ++j) s[j] = 0.0f;
  size_t base = (size_t)blockIdx.x * 2048 + tid;
#pragma unroll
  for (int k = 0; k < 8; ++k) {
    float4 P = G[base + (size_t)k * 256];
    s[0] += P.x; s[1] += P.y; s[2] += P.z;
    s[3] = fmaf(P.x, P.x, s[3]); s[4] = fmaf(P.y, P.y, s[4]); s[5] = fmaf(P.z, P.z, s[5]);
    s[6] = fmaf(P.x, P.y, s[6]); s[7] = fmaf(P.x, P.z, s[7]); s[8] = fmaf(P.y, P.z, s[8]);
  }
#pragma unroll
  for (int j = 0; j < 9; ++j) sr[tid * 9 + j] = s[j];
  __syncthreads();
  if (tid < 9) {
    float acc = 0;
    for (int r = 0; r < 256; ++r) acc += sr[r * 9 + tid];
    gmom[blockIdx.x * 9 + tid] = acc;
  }
}

// ---------------------------------------------------------------------------
// K2: stats1 — analytic BN1 stats from coord moments (1 block, 64 threads)
// ---------------------------------------------------------------------------
__global__ void stats1_kernel(const float* __restrict__ gmom,
                              const float* __restrict__ W1, const float* __restrict__ b1,
                              const float* __restrict__ g1, const float* __restrict__ be1,
                              float* __restrict__ s1out)
{
  __shared__ double m[9];
  if (threadIdx.x < 9) {
    double s = 0;
    for (int r = 0; r < 256; ++r) s += (double)gmom[r * 9 + threadIdx.x];
    m[threadIdx.x] = s / (double)SAMP;
  }
  __syncthreads();
  int c = threadIdx.x;  // 0..63
  double Ex = m[0], Ey = m[1], Ez = m[2];
  double Exx = m[3], Eyy = m[4], Ezz = m[5], Exy = m[6], Exz = m[7], Eyz = m[8];
  double wx = W1[c * 3 + 0], wy = W1[c * 3 + 1], wz = W1[c * 3 + 2], b = b1[c];
  double dot = wx * Ex + wy * Ey + wz * Ez;
  double mean = dot + b;
  double Ey2 = wx * wx * Exx + wy * wy * Eyy + wz * wz * Ezz
             + 2.0 * (wx * wy * Exy + wx * wz * Exz + wy * wz * Eyz)
             + 2.0 * b * dot + b * b;
  double var = Ey2 - mean * mean;
  double sc = (double)g1[c] / sqrt(var + 1e-5);
  s1out[c] = (float)sc;
  s1out[64 + c] = (float)((double)be1[c] - mean * sc);
}

// ---------------------------------------------------------------------------
// K3: z moments — recompute z1 from G, accumulate sum_z (64) and sum z z^T (64x64)
// ---------------------------------------------------------------------------
__global__ __launch_bounds__(256) void zmom_kernel(const float4* __restrict__ G,
                                                   const float* __restrict__ W1,
                                                   const float* __restrict__ b1,
                                                   const float* __restrict__ s1,
                                                   float* __restrict__ zzp)
{
  __shared__ float zt[128][68];     // rows 16B-aligned
  __shared__ float szred[4][64];

  const int tid = threadIdx.x;
  const int c = tid & 63;
  const int srow = tid >> 6;
  const float w1x = W1[c * 3 + 0], w1y = W1[c * 3 + 1], w1z = W1[c * 3 + 2];
  const float bb = b1[c], sc = s1[c], sh = s1[64 + c];

  const int R = tid >> 4;
  const int C = tid & 15;
  float acc[4][4];
#pragma unroll
  for (int i = 0; i < 4; ++i)
#pragma unroll
    for (int j = 0; j < 4; ++j) acc[i][j] = 0.0f;
  float szpart = 0.0f;

  const size_t sbase = (size_t)blockIdx.x * 1024;
  for (int t = 0; t < 8; ++t) {
    size_t s0 = sbase + (size_t)t * 128;
#pragma unroll 4
    for (int k = 0; k < 32; ++k) {
      int sl = srow + k * 4;
      float4 g = G[s0 + sl];
      float y = fmaf(w1z, g.z, fmaf(w1y, g.y, fmaf(w1x, g.x, bb)));
      float z = fmaxf(fmaf(sc, y, sh), 0.0f);
      zt[sl][c] = z;
      szpart += z;
    }
    __syncthreads();
#pragma unroll 4
    for (int s = 0; s < 128; ++s) {
      float4 va = *(const float4*)&zt[s][R * 4];
      float4 vb = *(const float4*)&zt[s][C * 4];
      acc[0][0] = fmaf(va.x, vb.x, acc[0][0]); acc[0][1] = fmaf(va.x, vb.y, acc[0][1]);
      acc[0][2] = fmaf(va.x, vb.z, acc[0][2]); acc[0][3] = fmaf(va.x, vb.w, acc[0][3]);
      acc[1][0] = fmaf(va.y, vb.x, acc[1][0]); acc[1][1] = fmaf(va.y, vb.y, acc[1][1]);
      acc[1][2] = fmaf(va.y, vb.z, acc[1][2]); acc[1][3] = fmaf(va.y, vb.w, acc[1][3]);
      acc[2][0] = fmaf(va.z, vb.x, acc[2][0]); acc[2][1] = fmaf(va.z, vb.y, acc[2][1]);
      acc[2][2] = fmaf(va.z, vb.z, acc[2][2]); acc[2][3] = fmaf(va.z, vb.w, acc[2][3]);
      acc[3][0] = fmaf(va.w, vb.x, acc[3][0]); acc[3][1] = fmaf(va.w, vb.y, acc[3][1]);
      acc[3][2] = fmaf(va.w, vb.z, acc[3][2]); acc[3][3] = fmaf(va.w, vb.w, acc[3][3]);
    }
    __syncthreads();
  }

  szred[srow][c] = szpart;
  float* out = zzp + (size_t)blockIdx.x * ZZW;
#pragma unroll
  for (int i = 0; i < 4; ++i)
#pragma unroll
    for (int j = 0; j < 4; ++j)
      out[(R * 4 + i) * 64 + (C * 4 + j)] = acc[i][j];
  __syncthreads();
  if (tid < 64)
    out[4096 + tid] = szred[0][tid] + szred[1][tid] + szred[2][tid] + szred[3][tid];
}

// ---------------------------------------------------------------------------
// K4: reduce zz partials over blocks -> double
// ---------------------------------------------------------------------------
__global__ void zzred_kernel(const float* __restrict__ zzp, double* __restrict__ zzs)
{
  int j = blockIdx.x * 256 + threadIdx.x;
  if (j < ZZW) {
    double s = 0;
    for (int b = 0; b < NBLK_ZZ; ++b) s += (double)zzp[(size_t)b * ZZW + j];
    zzs[j] = s;
  }
}

// ---------------------------------------------------------------------------
// K5: stats2 — BN2 stats via quadratic form; ALSO splits W2 into bf16 hi/lo
// (written into the dead zzp region) for the MFMA output pass.
// 128 blocks x 64 threads.
// ---------------------------------------------------------------------------
__global__ void stats2_kernel(const double* __restrict__ zzs,
                              const float* __restrict__ W2, const float* __restrict__ b2,
                              const float* __restrict__ g2, const float* __restrict__ be2,
                              float* __restrict__ s2out,
                              ushort* __restrict__ w2h, ushort* __restrict__ w2l)
{
  int d = blockIdx.x;
  int c = threadIdx.x;  // 0..63

  // W2 hi/lo bf16 split (one thread per element)
  {
    int idx = d * 64 + c;
    float w = W2[idx];
    ushort h = f2bf(w);
    float wh = __uint_as_float((unsigned)h << 16);
    ushort l = f2bf(w - wh);
    w2h[idx] = h;
    w2l[idx] = l;
  }

  double w_c = (double)W2[(size_t)d * 64 + c];
  double h = 0;
  for (int c2 = 0; c2 < 64; ++c2)
    h += (double)W2[(size_t)d * 64 + c2] * zzs[c * 64 + c2];
  double quad = w_c * h;
  double dz = w_c * zzs[4096 + c];
#pragma unroll
  for (int o = 32; o >= 1; o >>= 1) {
    quad += __shfl_down(quad, o, 64);
    dz += __shfl_down(dz, o, 64);
  }
  if (c == 0) {
    double S = (double)SAMP, b = (double)b2[d];
    double mean = dz / S + b;
    double Ey2 = (quad + 2.0 * b * dz) / S + b * b;
    double var = Ey2 - mean * mean;
    double sc = (double)g2[d] / sqrt(var + 1e-5);
    s2out[d] = (float)sc;
    s2out[128 + d] = (float)((double)be2[d] - mean * sc);
  }
}

// ---------------------------------------------------------------------------
// K6: output pass — split-bf16 MFMA GEMM. Block = 256 thr (4 waves) owns 128
// samples x 128 channels. Stage zh/zl [128][72] bf16 in LDS (one barrier).
// Each wave owns 32 channels (2 n-tiles of 16), B-frags (w2 hi/lo) resident
// in VGPRs; loops 8 M-tiles of 16 samples: 4x ds_read_b128 A-frags + 12x
// mfma_f32_16x16x32_bf16 (hi*hi + hi*lo + lo*hi). A: row=l&15, k=(l>>4)*8+j;
// B: col=l&15, same k; C/D: col=lane&15, row=(lane>>4)*4+reg (m89-verified).
// HBM-write-bound by construction (~256MB -> ~45us). 4096 blocks.
// ---------------------------------------------------------------------------
__global__ __launch_bounds__(256) void out_kernel(const float4* __restrict__ G,
                                                  const float* __restrict__ W1,
                                                  const float* __restrict__ b1,
                                                  const float* __restrict__ s1,
                                                  const ushort* __restrict__ w2h,
                                                  const ushort* __restrict__ w2l,
                                                  const float* __restrict__ b2,
                                                  const float* __restrict__ s2,
                                                  float* __restrict__ out)
{
  __shared__ ushort zh[128][72];   // bf16 hi, row pitch 144B (16B-aligned)
  __shared__ ushort zl[128][72];   // bf16 lo

  const int tid = threadIdx.x;
  const int wave = tid >> 6;
  const int lane = tid & 63;
  const size_t sbase = (size_t)blockIdx.x * 128;

  // ---- stage z hi/lo: thread (zc, wave) handles channel zc, samples wave+4k
  {
    const int zc = tid & 63;
    const float w1x = W1[zc * 3 + 0], w1y = W1[zc * 3 + 1], w1z = W1[zc * 3 + 2];
    const float bb1 = b1[zc], sc1 = s1[zc], sh1 = s1[64 + zc];
#pragma unroll 4
    for (int k = 0; k < 32; ++k) {
      int s = (tid >> 6) + k * 4;
      float4 g = G[sbase + s];
      float y = fmaf(w1z, g.z, fmaf(w1y, g.y, fmaf(w1x, g.x, bb1)));
      float z = fmaxf(fmaf(sc1, y, sh1), 0.0f);
      ushort h = f2bf(z);
      float zhf = __uint_as_float((unsigned)h << 16);
      zh[s][zc] = h;
      zl[s][zc] = f2bf(z - zhf);
    }
  }

  // ---- B-fragments: wave owns channels d = wave*32 + {0,16} + (lane&15)
  const int col = lane & 15;
  const int krow = (lane >> 4) * 8;
  const int d0 = wave * 32 + col;
  const int d1 = d0 + 16;
  short8_b Bh0[2], Bl0[2], Bh1[2], Bl1[2];
#pragma unroll
  for (int kk = 0; kk < 2; ++kk) {
    int c0 = kk * 32 + krow;
    Bh0[kk] = *(const short8_b*)(w2h + d0 * 64 + c0);
    Bl0[kk] = *(const short8_b*)(w2l + d0 * 64 + c0);
    Bh1[kk] = *(const short8_b*)(w2h + d1 * 64 + c0);
    Bl1[kk] = *(const short8_b*)(w2l + d1 * 64 + c0);
  }
  const float bv0 = b2[d0], scv0 = s2[d0], shv0 = s2[128 + d0];
  const float bv1 = b2[d1], scv1 = s2[d1], shv1 = s2[128 + d1];

  __syncthreads();

  // ---- M-loop: 8 tiles of 16 samples
  for (int m = 0; m < 8; ++m) {
    const int row = m * 16 + col;
    short8_b Ah[2], Al[2];
#pragma unroll
    for (int kk = 0; kk < 2; ++kk) {
      int c0 = kk * 32 + krow;
      Ah[kk] = *(const short8_b*)&zh[row][c0];
      Al[kk] = *(const short8_b*)&zl[row][c0];
    }
    f32x4 acc0 = {0.f, 0.f, 0.f, 0.f};
    f32x4 acc1 = {0.f, 0.f, 0.f, 0.f};
#pragma unroll
    for (int kk = 0; kk < 2; ++kk) {
      acc0 = __builtin_amdgcn_mfma_f32_16x16x32_bf16(Ah[kk], Bh0[kk], acc0, 0, 0, 0);
      acc0 = __builtin_amdgcn_mfma_f32_16x16x32_bf16(Ah[kk], Bl0[kk], acc0, 0, 0, 0);
      acc0 = __builtin_amdgcn_mfma_f32_16x16x32_bf16(Al[kk], Bh0[kk], acc0, 0, 0, 0);
      acc1 = __builtin_amdgcn_mfma_f32_16x16x32_bf16(Ah[kk], Bh1[kk], acc1, 0, 0, 0);
      acc1 = __builtin_amdgcn_mfma_f32_16x16x32_bf16(Ah[kk], Bl1[kk], acc1, 0, 0, 0);
      acc1 = __builtin_amdgcn_mfma_f32_16x16x32_bf16(Al[kk], Bh1[kk], acc1, 0, 0, 0);
    }
    // epilogue: D row = (lane>>4)*4 + i (sample), col = lane&15 (channel)
    const size_t srow = sbase + m * 16 + (lane >> 4) * 4;
#pragma unroll
    for (int i = 0; i < 4; ++i) {
      float o0 = fmaxf(fmaf(scv0, acc0[i] + bv0, shv0), 0.0f);
      float o1 = fmaxf(fmaf(scv1, acc1[i] + bv1, shv1), 0.0f);
      out[(srow + i) * 128 + d0] = o0;
      out[(srow + i) * 128 + d1] = o1;
    }
  }
}

// ---------------------------------------------------------------------------
extern "C" void kernel_launch(void* const* d_in, const int* in_sizes, int n_in,
                              void* d_out, int out_size, void* d_ws, size_t ws_size,
                              hipStream_t stream)
{
  const float* points  = (const float*)d_in[0];
  const float* queries = (const float*)d_in[1];
  const float* W1      = (const float*)d_in[2];
  const float* b1      = (const float*)d_in[3];
  const float* gamma1  = (const float*)d_in[4];
  const float* beta1   = (const float*)d_in[5];
  const float* W2      = (const float*)d_in[6];
  const float* b2      = (const float*)d_in[7];
  const float* gamma2  = (const float*)d_in[8];
  const float* beta2   = (const float*)d_in[9];

  char* ws = (char*)d_ws;
  float4* G    = (float4*)(ws + OFF_G);
  float*  gmom = (float*)(ws + OFF_GMOM);
  float*  s1   = (float*)(ws + OFF_S1);
  float*  zzp  = (float*)(ws + OFF_ZZP);
  double* zzs  = (double*)(ws + OFF_ZZS);
  float*  s2   = (float*)(ws + OFF_S2);
  ushort* w2h  = (ushort*)(ws + OFF_W2H);
  ushort* w2l  = (ushort*)(ws + OFF_W2L);
  float*  out  = (float*)d_out;

  knn_kernel<<<512, 1024, 0, stream>>>(points, queries, G);
  gmom_kernel<<<256, 256, 0, stream>>>(G, gmom);
  stats1_kernel<<<1, 64, 0, stream>>>(gmom, W1, b1, gamma1, beta1, s1);
  zmom_kernel<<<NBLK_ZZ, 256, 0, stream>>>(G, W1, b1, s1, zzp);
  zzred_kernel<<<17, 256, 0, stream>>>(zzp, zzs);
  stats2_kernel<<<128, 64, 0, stream>>>(zzs, W2, b2, gamma2, beta2, s2, w2h, w2l);
  out_kernel<<<4096, 256, 0, stream>>>(G, W1, b1, s1, w2h, w2l, b2, s2, out);
}

// Round 7
// 230.662 us; speedup vs baseline: 4.7418x; 1.2306x over previous
//
#include <hip/hip_runtime.h>
#include <cmath>

// Problem constants
constexpr int BB = 4, LL = 8, NPTS = 4096, MQ = 1024, KNNK = 16;
constexpr int C1 = 64, C2 = 128;
constexpr int NSLICE = BB * LL;                       // 32
constexpr long long SAMP = (long long)NSLICE * MQ * KNNK;  // 524288 samples
constexpr int NBLK_ZZ = 512;
constexpr int ZZW = C1 * C1 + C1;                     // 4160 (full 64x64 + sum_z)

// Workspace layout (bytes)
constexpr size_t OFF_G    = 0;                                   // float4[SAMP] = 8 MB
constexpr size_t OFF_GMOM = (size_t)8 * 1024 * 1024;             // float[512*9]
constexpr size_t OFF_S1   = OFF_GMOM + 20480;                    // float[128]: scale1,shift1
constexpr size_t OFF_ZZP  = OFF_S1 + 1024;                       // float[NBLK_ZZ*ZZW]
constexpr size_t OFF_ZZS  = OFF_ZZP + (size_t)NBLK_ZZ * ZZW * 4; // double[ZZW]
constexpr size_t OFF_S2   = OFF_ZZS + (size_t)ZZW * 8;           // float[256]: scale2,shift2
// W2 hi/lo bf16 splits: reuse the zzp region (dead after zzred, before stats2)
constexpr size_t OFF_W2H  = OFF_ZZP;                             // ushort[8192]
constexpr size_t OFF_W2L  = OFF_ZZP + 16384;                     // ushort[8192]

typedef __attribute__((ext_vector_type(8))) short short8_b;   // 8 bf16 (4 VGPRs)
typedef __attribute__((ext_vector_type(4))) float f32x4;

__device__ inline ushort f2bf(float f) {        // RNE float -> bf16 bits
  unsigned u = __float_as_uint(f);
  return (ushort)((u + 0x7fffu + ((u >> 16) & 1u)) >> 16);
}

// ---------------------------------------------------------------------------
// K1: per-slice KNN + gather + fused coordinate moments (bitonic seed +
// segmented ballot inserts; see R2-R5 notes). 512 blocks x 1024 threads.
// ---------------------------------------------------------------------------
__global__ __launch_bounds__(1024, 8) void knn_kernel(const float* __restrict__ pts,
                                                      const float* __restrict__ qrs,
                                                      float4* __restrict__ G,
                                                      float* __restrict__ gmom)
{
#pragma clang fp contract(off)
  __shared__ float4 sp[NPTS];   // (x,y,z,p2) = 64 KB
  __shared__ float smom[16][9];
  const int tid = threadIdx.x;
  const int bl = blockIdx.x >> 4;    // slice (32)
  const int qt = blockIdx.x & 15;    // 16 query tiles of 64
  const int wave = tid >> 6;
  const int lane = tid & 63;
  const float INF = 3.402823466e38f;

  const float* pb = pts + (size_t)bl * NPTS * 3;
  for (int p = tid; p < NPTS; p += 1024) {
    float x = pb[p * 3 + 0], y = pb[p * 3 + 1], z = pb[p * 3 + 2];
    float pp = (x * x + y * y) + z * z;       // plain rounding
    sp[p] = make_float4(x, y, z, pp);
  }
  __syncthreads();

  const int qbase = qt * 64 + wave * 4;
  const float* qp = qrs + ((size_t)bl * MQ + qbase) * 3;
  const float qxA = qp[0], qyA = qp[1], qzA = qp[2];
  const float qxB = qp[3], qyB = qp[4], qzB = qp[5];
  const float qxC = qp[6], qyC = qp[7], qzC = qp[8];
  const float qxD = qp[9], qyD = qp[10], qzD = qp[11];
  const float q2A = (qxA * qxA + qyA * qyA) + qzA * qzA;   // plain rounding
  const float q2B = (qxB * qxB + qyB * qyB) + qzB * qzB;
  const float q2C = (qxC * qxC + qyC * qyC) + qzC * qzC;
  const float q2D = (qxD * qxD + qyD * qyD) + qzD * qzD;

  const int seg = lane >> 4;
  const bool segHead = (lane & 15) == 0;

  float Ld; int Li;
  float tauA, tauB, tauC, tauD;

  // ---- seed (i = 0): bitonic sort of 64 (d, lane) keys per query ----
  {
    float4 P = sp[lane];
    float pqA = fmaf(P.z, qzA, fmaf(P.y, qyA, P.x * qxA));
    float pqB = fmaf(P.z, qzB, fmaf(P.y, qyB, P.x * qxB));
    float pqC = fmaf(P.z, qzC, fmaf(P.y, qyC, P.x * qxC));
    float pqD = fmaf(P.z, qzD, fmaf(P.y, qyD, P.x * qxD));
    float dA = fmaf(-2.0f, pqA, q2A + P.w);
    float dB = fmaf(-2.0f, pqB, q2B + P.w);
    float dC = fmaf(-2.0f, pqC, q2C + P.w);
    float dD = fmaf(-2.0f, pqD, q2D + P.w);

    unsigned uA = __float_as_uint(dA); uA = (uA & 0x80000000u) ? ~uA : (uA | 0x80000000u);
    unsigned uB = __float_as_uint(dB); uB = (uB & 0x80000000u) ? ~uB : (uB | 0x80000000u);
    unsigned uC = __float_as_uint(dC); uC = (uC & 0x80000000u) ? ~uC : (uC | 0x80000000u);
    unsigned uD = __float_as_uint(dD); uD = (uD & 0x80000000u) ? ~uD : (uD | 0x80000000u);
    unsigned long long kA = ((unsigned long long)uA << 6) | (unsigned)lane;
    unsigned long long kB = ((unsigned long long)uB << 6) | (unsigned)lane;
    unsigned long long kC = ((unsigned long long)uC << 6) | (unsigned)lane;
    unsigned long long kD = ((unsigned long long)uD << 6) | (unsigned)lane;

#pragma unroll
    for (int k = 2; k <= 64; k <<= 1) {
#pragma unroll
      for (int j = k >> 1; j >= 1; j >>= 1) {
        const bool selMin = ((lane & j) == 0) == ((lane & k) == 0);
        unsigned long long pA = __shfl_xor(kA, j, 64);
        unsigned long long pB = __shfl_xor(kB, j, 64);
        unsigned long long pC = __shfl_xor(kC, j, 64);
        unsigned long long pD = __shfl_xor(kD, j, 64);
        kA = ((kA < pA) == selMin) ? kA : pA;
        kB = ((kB < pB) == selMin) ? kB : pB;
        kC = ((kC < pC) == selMin) ? kC : pC;
        kD = ((kD < pD) == selMin) ? kD : pD;
      }
    }

    const int src = lane & 15;
    unsigned long long rA = __shfl(kA, src, 64);
    unsigned long long rB = __shfl(kB, src, 64);
    unsigned long long rC = __shfl(kC, src, 64);
    unsigned long long rD = __shfl(kD, src, 64);
    unsigned long long r0 = (seg & 1) ? rB : rA;
    unsigned long long r1 = (seg & 1) ? rD : rC;
    unsigned long long rr = (seg & 2) ? r1 : r0;
    unsigned um = (unsigned)(rr >> 6);
    um = (um & 0x80000000u) ? (um & 0x7fffffffu) : ~um;    // inverse map
    Ld = __uint_as_float(um);
    Li = (int)(rr & 63u);
    tauA = __shfl(Ld, 15, 64);
    tauB = __shfl(Ld, 31, 64);
    tauC = __shfl(Ld, 47, 64);
    tauD = __shfl(Ld, 63, 64);
  }

  // ---- main scan: i = 1..63 ----
  for (int i = 1; i < 64; ++i) {
    float4 P = sp[i * 64 + lane];
    float pqA = fmaf(P.z, qzA, fmaf(P.y, qyA, P.x * qxA));
    float pqB = fmaf(P.z, qzB, fmaf(P.y, qyB, P.x * qxB));
    float pqC = fmaf(P.z, qzC, fmaf(P.y, qyC, P.x * qxC));
    float pqD = fmaf(P.z, qzD, fmaf(P.y, qyD, P.x * qxD));
    float dA = fmaf(-2.0f, pqA, q2A + P.w);
    float dB = fmaf(-2.0f, pqB, q2B + P.w);
    float dC = fmaf(-2.0f, pqC, q2C + P.w);
    float dD = fmaf(-2.0f, pqD, q2D + P.w);

    unsigned long long mA = __ballot(dA < tauA);
    unsigned long long mB = __ballot(dB < tauB);
    unsigned long long mC = __ballot(dC < tauC);
    unsigned long long mD = __ballot(dD < tauD);

    if (mA | mB | mC | mD) {
      do {
        float vA = INF, vB = INF, vC = INF, vD = INF;
        int iA = 0, iB = 0, iC = 0, iD = 0;
        if (mA) { int b = (int)__builtin_ctzll(mA); mA &= mA - 1;
                  vA = __shfl(dA, b, 64); iA = i * 64 + b; }
        if (mB) { int b = (int)__builtin_ctzll(mB); mB &= mB - 1;
                  vB = __shfl(dB, b, 64); iB = i * 64 + b; }
        if (mC) { int b = (int)__builtin_ctzll(mC); mC &= mC - 1;
                  vC = __shfl(dC, b, 64); iC = i * 64 + b; }
        if (mD) { int b = (int)__builtin_ctzll(mD); mD &= mD - 1;
                  vD = __shfl(dD, b, 64); iD = i * 64 + b; }
        float v0 = (seg & 1) ? vB : vA;
        float v1 = (seg & 1) ? vD : vC;
        float v  = (seg & 2) ? v1 : v0;
        int  i0 = (seg & 1) ? iB : iA;
        int  i1 = (seg & 1) ? iD : iC;
        int  vi = (seg & 2) ? i1 : i0;
        float pd = __shfl_up(Ld, 1, 64);
        int   pi = __shfl_up(Li, 1, 64);
        if (segHead) pd = -INF;
        bool gt  = Ld > v;     // strict: equals keep rank (lower idx first)
        bool gtp = pd > v;
        Ld = gt ? (gtp ? pd : v) : Ld;
        Li = gt ? (gtp ? pi : vi) : Li;
      } while (mA | mB | mC | mD);
      tauA = __shfl(Ld, 15, 64);
      tauB = __shfl(Ld, 31, 64);
      tauC = __shfl(Ld, 47, 64);
      tauD = __shfl(Ld, 63, 64);
    }
  }

  float4 P = sp[Li];
  G[((size_t)bl * MQ + qbase + seg) * KNNK + (lane & 15)] =
      make_float4(P.x, P.y, P.z, 0.0f);

  // ---- fused coordinate moments (every lane holds exactly one sample) ----
  float mm[9];
  mm[0] = P.x; mm[1] = P.y; mm[2] = P.z;
  mm[3] = P.x * P.x; mm[4] = P.y * P.y; mm[5] = P.z * P.z;
  mm[6] = P.x * P.y; mm[7] = P.x * P.z; mm[8] = P.y * P.z;
#pragma unroll
  for (int j = 0; j < 9; ++j) {
#pragma unroll
    for (int o = 32; o >= 1; o >>= 1) mm[j] += __shfl_xor(mm[j], o, 64);
  }
  if (lane == 0) {
#pragma unroll
    for (int j = 0; j < 9; ++j) smom[wave][j] = mm[j];
  }
  __syncthreads();
  if (tid < 9) {
    float a = 0;
    for (int w = 0; w < 16; ++w) a += smom[w][tid];
    gmom[blockIdx.x * 9 + tid] = a;
  }
}

// ---------------------------------------------------------------------------
// K2: stats1 — analytic BN1 stats from coord moments (1 block, 576 threads:
// 9 waves reduce one moment each over 512 blocks, then 64 threads finish)
// ---------------------------------------------------------------------------
__global__ void stats1_kernel(const float* __restrict__ gmom,
                              const float* __restrict__ W1, const float* __restrict__ b1,
                              const float* __restrict__ g1, const float* __restrict__ be1,
                              float* __restrict__ s1out)
{
  __shared__ double m[9];
  const int t = threadIdx.x;
  const int mom = t >> 6, lane = t & 63;
  if (mom < 9) {
    double s = 0;
    for (int b = lane; b < 512; b += 64) s += (double)gmom[b * 9 + mom];
#pragma unroll
    for (int o = 32; o >= 1; o >>= 1) s += __shfl_down(s, o, 64);
    if (lane == 0) m[mom] = s / (double)SAMP;
  }
  __syncthreads();
  if (t < 64) {
    int c = t;
    double Ex = m[0], Ey = m[1], Ez = m[2];
    double Exx = m[3], Eyy = m[4], Ezz = m[5], Exy = m[6], Exz = m[7], Eyz = m[8];
    double wx = W1[c * 3 + 0], wy = W1[c * 3 + 1], wz = W1[c * 3 + 2], b = b1[c];
    double dot = wx * Ex + wy * Ey + wz * Ez;
    double mean = dot + b;
    double Ey2 = wx * wx * Exx + wy * wy * Eyy + wz * wz * Ezz
               + 2.0 * (wx * wy * Exy + wx * wz * Exz + wy * wz * Eyz)
               + 2.0 * b * dot + b * b;
    double var = Ey2 - mean * mean;
    double sc = (double)g1[c] / sqrt(var + 1e-5);
    s1out[c] = (float)sc;
    s1out[64 + c] = (float)((double)be1[c] - mean * sc);
  }
}

// ---------------------------------------------------------------------------
// K3: z moments via split-bf16 MFMA. zz = Z^T Z (64x64) + sum_z, per block of
// 1024 samples (8 tiles of 128). Z staged [ch][136] bf16 hi/lo in LDS
// (272B rows: 16B-aligned, ~2-way-bank frag reads; staging writes
// conflict-free via lane=sample-pair mapping). Per K-chunk of 32 samples:
// wave w owns channel-row w -> A=ch-block w, B=ch-blocks 0..3; 12 mfma
// (3-term hi/lo) + 2 mfma vs ones-B for sum_z. Frag mappings identical to
// the validated out_kernel. 512 blocks x 256 threads.
// ---------------------------------------------------------------------------
__global__ __launch_bounds__(256) void zmom_kernel(const float4* __restrict__ G,
                                                   const float* __restrict__ W1,
                                                   const float* __restrict__ b1,
                                                   const float* __restrict__ s1,
                                                   float* __restrict__ zzp)
{
  __shared__ ushort zh[64][136];
  __shared__ ushort zl[64][136];

  const int tid = threadIdx.x;
  const int wave = tid >> 6;
  const int lane = tid & 63;
  const int p = lane;                  // sample pair 0..63
  const int c0base = wave * 16;        // staging channel block
  const int col = lane & 15;
  const int kr = lane >> 4;            // 0..3

  short8_b onesH;
#pragma unroll
  for (int j = 0; j < 8; ++j) onesH[j] = (short)0x3f80;   // bf16 1.0

  f32x4 acc0 = {0.f,0.f,0.f,0.f}, acc1 = {0.f,0.f,0.f,0.f};
  f32x4 acc2 = {0.f,0.f,0.f,0.f}, acc3 = {0.f,0.f,0.f,0.f};
  f32x4 accs = {0.f,0.f,0.f,0.f};

  const size_t sbase = (size_t)blockIdx.x * 1024;
  for (int t = 0; t < 8; ++t) {
    const size_t s0 = sbase + (size_t)t * 128;
    // ---- stage: thread handles sample pair (2p, 2p+1), channels c0base..+15
    float4 g0 = G[s0 + 2 * p];
    float4 g1 = G[s0 + 2 * p + 1];
#pragma unroll
    for (int i = 0; i < 16; ++i) {
      const int c = c0base + i;
      const float w1x = W1[c * 3 + 0], w1y = W1[c * 3 + 1], w1z = W1[c * 3 + 2];
      const float bb1 = b1[c], sc1 = s1[c], sh1 = s1[64 + c];
      float y0 = fmaf(w1z, g0.z, fmaf(w1y, g0.y, fmaf(w1x, g0.x, bb1)));
      float y1 = fmaf(w1z, g1.z, fmaf(w1y, g1.y, fmaf(w1x, g1.x, bb1)));
      float z0 = fmaxf(fmaf(sc1, y0, sh1), 0.0f);
      float z1 = fmaxf(fmaf(sc1, y1, sh1), 0.0f);
      ushort h0 = f2bf(z0), h1 = f2bf(z1);
      float h0f = __uint_as_float((unsigned)h0 << 16);
      float h1f = __uint_as_float((unsigned)h1 << 16);
      ushort l0 = f2bf(z0 - h0f), l1 = f2bf(z1 - h1f);
      ((unsigned*)&zh[0][0])[c * 68 + p] = (unsigned)h0 | ((unsigned)h1 << 16);
      ((unsigned*)&zl[0][0])[c * 68 + p] = (unsigned)l0 | ((unsigned)l1 << 16);
    }
    __syncthreads();
    // ---- mfma: 4 K-chunks of 32 samples
#pragma unroll
    for (int kt = 0; kt < 4; ++kt) {
      const int soff = kt * 32 + kr * 8;
      short8_b Ah = *(const short8_b*)&zh[wave * 16 + col][soff];
      short8_b Al = *(const short8_b*)&zl[wave * 16 + col][soff];
      short8_b B0h = *(const short8_b*)&zh[ 0 + col][soff];
      short8_b B0l = *(const short8_b*)&zl[ 0 + col][soff];
      short8_b B1h = *(const short8_b*)&zh[16 + col][soff];
      short8_b B1l = *(const short8_b*)&zl[16 + col][soff];
      short8_b B2h = *(const short8_b*)&zh[32 + col][soff];
      short8_b B2l = *(const short8_b*)&zl[32 + col][soff];
      short8_b B3h = *(const short8_b*)&zh[48 + col][soff];
      short8_b B3l = *(const short8_b*)&zl[48 + col][soff];
      acc0 = __builtin_amdgcn_mfma_f32_16x16x32_bf16(Ah, B0h, acc0, 0, 0, 0);
      acc0 = __builtin_amdgcn_mfma_f32_16x16x32_bf16(Ah, B0l, acc0, 0, 0, 0);
      acc0 = __builtin_amdgcn_mfma_f32_16x16x32_bf16(Al, B0h, acc0, 0, 0, 0);
      acc1 = __builtin_amdgcn_mfma_f32_16x16x32_bf16(Ah, B1h, acc1, 0, 0, 0);
      acc1 = __builtin_amdgcn_mfma_f32_16x16x32_bf16(Ah, B1l, acc1, 0, 0, 0);
      acc1 = __builtin_amdgcn_mfma_f32_16x16x32_bf16(Al, B1h, acc1, 0, 0, 0);
      acc2 = __builtin_amdgcn_mfma_f32_16x16x32_bf16(Ah, B2h, acc2, 0, 0, 0);
      acc2 = __builtin_amdgcn_mfma_f32_16x16x32_bf16(Ah, B2l, acc2, 0, 0, 0);
      acc2 = __builtin_amdgcn_mfma_f32_16x16x32_bf16(Al, B2h, acc2, 0, 0, 0);
      acc3 = __builtin_amdgcn_mfma_f32_16x16x32_bf16(Ah, B3h, acc3, 0, 0, 0);
      acc3 = __builtin_amdgcn_mfma_f32_16x16x32_bf16(Ah, B3l, acc3, 0, 0, 0);
      acc3 = __builtin_amdgcn_mfma_f32_16x16x32_bf16(Al, B3h, acc3, 0, 0, 0);
      accs = __builtin_amdgcn_mfma_f32_16x16x32_bf16(Ah, onesH, accs, 0, 0, 0);
      accs = __builtin_amdgcn_mfma_f32_16x16x32_bf16(Al, onesH, accs, 0, 0, 0);
    }
    __syncthreads();
  }

  // epilogue: D row = A-channel = wave*16 + kr*4 + i, col = B-channel block*16 + (lane&15)
  float* outp = zzp + (size_t)blockIdx.x * ZZW;
#pragma unroll
  for (int i = 0; i < 4; ++i) {
    const int row = wave * 16 + kr * 4 + i;
    outp[row * 64 +  0 + col] = acc0[i];
    outp[row * 64 + 16 + col] = acc1[i];
    outp[row * 64 + 32 + col] = acc2[i];
    outp[row * 64 + 48 + col] = acc3[i];
  }
  if (col == 0) {
#pragma unroll
    for (int i = 0; i < 4; ++i)
      outp[4096 + wave * 16 + kr * 4 + i] = accs[i];
  }
}

// ---------------------------------------------------------------------------
// K4: reduce zz partials over blocks -> double
// ---------------------------------------------------------------------------
__global__ void zzred_kernel(const float* __restrict__ zzp, double* __restrict__ zzs)
{
  int j = blockIdx.x * 256 + threadIdx.x;
  if (j < ZZW) {
    double s = 0;
    for (int b = 0; b < NBLK_ZZ; ++b) s += (double)zzp[(size_t)b * ZZW + j];
    zzs[j] = s;
  }
}

// ---------------------------------------------------------------------------
// K5: stats2 — BN2 stats via quadratic form; also splits W2 into bf16 hi/lo
// (into the dead zzp region) for the MFMA output pass. 128 blocks x 64 thr.
// ---------------------------------------------------------------------------
__global__ void stats2_kernel(const double* __restrict__ zzs,
                              const float* __restrict__ W2, const float* __restrict__ b2,
                              const float* __restrict__ g2, const float* __restrict__ be2,
                              float* __restrict__ s2out,
                              ushort* __restrict__ w2h, ushort* __restrict__ w2l)
{
  int d = blockIdx.x;
  int c = threadIdx.x;  // 0..63

  {
    int idx = d * 64 + c;
    float w = W2[idx];
    ushort h = f2bf(w);
    float wh = __uint_as_float((unsigned)h << 16);
    ushort l = f2bf(w - wh);
    w2h[idx] = h;
    w2l[idx] = l;
  }

  double w_c = (double)W2[(size_t)d * 64 + c];
  double h = 0;
  for (int c2 = 0; c2 < 64; ++c2)
    h += (double)W2[(size_t)d * 64 + c2] * zzs[c * 64 + c2];
  double quad = w_c * h;
  double dz = w_c * zzs[4096 + c];
#pragma unroll
  for (int o = 32; o >= 1; o >>= 1) {
    quad += __shfl_down(quad, o, 64);
    dz += __shfl_down(dz, o, 64);
  }
  if (c == 0) {
    double S = (double)SAMP, b = (double)b2[d];
    double mean = dz / S + b;
    double Ey2 = (quad + 2.0 * b * dz) / S + b * b;
    double var = Ey2 - mean * mean;
    double sc = (double)g2[d] / sqrt(var + 1e-5);
    s2out[d] = (float)sc;
    s2out[128 + d] = (float)((double)be2[d] - mean * sc);
  }
}

// ---------------------------------------------------------------------------
// K6: output pass — split-bf16 MFMA GEMM (see R6 notes). 4096 blocks.
// ---------------------------------------------------------------------------
__global__ __launch_bounds__(256) void out_kernel(const float4* __restrict__ G,
                                                  const float* __restrict__ W1,
                                                  const float* __restrict__ b1,
                                                  const float* __restrict__ s1,
                                                  const ushort* __restrict__ w2h,
                                                  const ushort* __restrict__ w2l,
                                                  const float* __restrict__ b2,
                                                  const float* __restrict__ s2,
                                                  float* __restrict__ out)
{
  __shared__ ushort zh[128][72];   // bf16 hi, row pitch 144B (16B-aligned)
  __shared__ ushort zl[128][72];   // bf16 lo

  const int tid = threadIdx.x;
  const int wave = tid >> 6;
  const int lane = tid & 63;
  const size_t sbase = (size_t)blockIdx.x * 128;

  {
    const int zc = tid & 63;
    const float w1x = W1[zc * 3 + 0], w1y = W1[zc * 3 + 1], w1z = W1[zc * 3 + 2];
    const float bb1 = b1[zc], sc1 = s1[zc], sh1 = s1[64 + zc];
#pragma unroll 4
    for (int k = 0; k < 32; ++k) {
      int s = (tid >> 6) + k * 4;
      float4 g = G[sbase + s];
      float y = fmaf(w1z, g.z, fmaf(w1y, g.y, fmaf(w1x, g.x, bb1)));
      float z = fmaxf(fmaf(sc1, y, sh1), 0.0f);
      ushort h = f2bf(z);
      float zhf = __uint_as_float((unsigned)h << 16);
      zh[s][zc] = h;
      zl[s][zc] = f2bf(z - zhf);
    }
  }

  const int col = lane & 15;
  const int krow = (lane >> 4) * 8;
  const int d0 = wave * 32 + col;
  const int d1 = d0 + 16;
  short8_b Bh0[2], Bl0[2], Bh1[2], Bl1[2];
#pragma unroll
  for (int kk = 0; kk < 2; ++kk) {
    int c0 = kk * 32 + krow;
    Bh0[kk] = *(const short8_b*)(w2h + d0 * 64 + c0);
    Bl0[kk] = *(const short8_b*)(w2l + d0 * 64 + c0);
    Bh1[kk] = *(const short8_b*)(w2h + d1 * 64 + c0);
    Bl1[kk] = *(const short8_b*)(w2l + d1 * 64 + c0);
  }
  const float bv0 = b2[d0], scv0 = s2[d0], shv0 = s2[128 + d0];
  const float bv1 = b2[d1], scv1 = s2[d1], shv1 = s2[128 + d1];

  __syncthreads();

  for (int m = 0; m < 8; ++m) {
    const int row = m * 16 + col;
    short8_b Ah[2], Al[2];
#pragma unroll
    for (int kk = 0; kk < 2; ++kk) {
      int c0 = kk * 32 + krow;
      Ah[kk] = *(const short8_b*)&zh[row][c0];
      Al[kk] = *(const short8_b*)&zl[row][c0];
    }
    f32x4 acc0 = {0.f, 0.f, 0.f, 0.f};
    f32x4 acc1 = {0.f, 0.f, 0.f, 0.f};
#pragma unroll
    for (int kk = 0; kk < 2; ++kk) {
      acc0 = __builtin_amdgcn_mfma_f32_16x16x32_bf16(Ah[kk], Bh0[kk], acc0, 0, 0, 0);
      acc0 = __builtin_amdgcn_mfma_f32_16x16x32_bf16(Ah[kk], Bl0[kk], acc0, 0, 0, 0);
      acc0 = __builtin_amdgcn_mfma_f32_16x16x32_bf16(Al[kk], Bh0[kk], acc0, 0, 0, 0);
      acc1 = __builtin_amdgcn_mfma_f32_16x16x32_bf16(Ah[kk], Bh1[kk], acc1, 0, 0, 0);
      acc1 = __builtin_amdgcn_mfma_f32_16x16x32_bf16(Ah[kk], Bl1[kk], acc1, 0, 0, 0);
      acc1 = __builtin_amdgcn_mfma_f32_16x16x32_bf16(Al[kk], Bh1[kk], acc1, 0, 0, 0);
    }
    const size_t srow = sbase + m * 16 + (lane >> 4) * 4;
#pragma unroll
    for (int i = 0; i < 4; ++i) {
      float o0 = fmaxf(fmaf(scv0, acc0[i] + bv0, shv0), 0.0f);
      float o1 = fmaxf(fmaf(scv1, acc1[i] + bv1, shv1), 0.0f);
      out[(srow + i) * 128 + d0] = o0;
      out[(srow + i) * 128 + d1] = o1;
    }
  }
}

// ---------------------------------------------------------------------------
extern "C" void kernel_launch(void* const* d_in, const int* in_sizes, int n_in,
                              void* d_out, int out_size, void* d_ws, size_t ws_size,
                              hipStream_t stream)
{
  const float* points  = (const float*)d_in[0];
  const float* queries = (const float*)d_in[1];
  const float* W1      = (const float*)d_in[2];
  const float* b1      = (const float*)d_in[3];
  const float* gamma1  = (const float*)d_in[4];
  const float* beta1   = (const float*)d_in[5];
  const float* W2      = (const float*)d_in[6];
  const float* b2      = (const float*)d_in[7];
  const float* gamma2  = (const float*)d_in[8];
  const float* beta2   = (const float*)d_in[9];

  char* ws = (char*)d_ws;
  float4* G    = (float4*)(ws + OFF_G);
  float*  gmom = (float*)(ws + OFF_GMOM);
  float*  s1   = (float*)(ws + OFF_S1);
  float*  zzp  = (float*)(ws + OFF_ZZP);
  double* zzs  = (double*)(ws + OFF_ZZS);
  float*  s2   = (float*)(ws + OFF_S2);
  ushort* w2h  = (ushort*)(ws + OFF_W2H);
  ushort* w2l  = (ushort*)(ws + OFF_W2L);
  float*  out  = (float*)d_out;

  knn_kernel<<<512, 1024, 0, stream>>>(points, queries, G, gmom);
  stats1_kernel<<<1, 576, 0, stream>>>(gmom, W1, b1, gamma1, beta1, s1);
  zmom_kernel<<<NBLK_ZZ, 256, 0, stream>>>(G, W1, b1, s1, zzp);
  zzred_kernel<<<17, 256, 0, stream>>>(zzp, zzs);
  stats2_kernel<<<128, 64, 0, stream>>>(zzs, W2, b2, gamma2, beta2, s2, w2h, w2l);
  out_kernel<<<4096, 256, 0, stream>>>(G, W1, b1, s1, w2h, w2l, b2, s2, out);
}